// Round 8
// baseline (496.177 us; speedup 1.0000x reference)
//
#include <hip/hip_runtime.h>
#include <math.h>

typedef unsigned short u16;
typedef unsigned int   u32;
typedef __attribute__((ext_vector_type(8))) short short8;
typedef __attribute__((ext_vector_type(4))) float floatx4;

#define MFMA16(a,b,c) __builtin_amdgcn_mfma_f32_16x16x32_bf16((a),(b),(c),0,0,0)

constexpr int BB  = 2;
constexpr int NT  = 2240;
constexpr int CD  = 384;
constexpr int NH  = 6;
constexpr int HD  = 64;
constexpr int HID = 1536;
constexpr int M   = BB * NT;          // 4480
constexpr int CS  = 5;                // attn column chunks
constexpr int CTILES = NT / 64 / CS;  // 7 col-tiles per chunk
constexpr float SCALE = 0.125f;

__device__ inline u16 f2bf(float f) {
  u32 u = __float_as_uint(f);
  u = (u + 0x7fffu + ((u >> 16) & 1u)) >> 16;
  return (u16)u;
}
__device__ inline float bf2f(u16 b) { return __uint_as_float(((u32)b) << 16); }

__device__ inline uint4 sum5_bf(uint4 a0, uint4 a1, uint4 a2, uint4 a3, uint4 a4) {
  union U { uint4 v; u16 h[8]; };
  U u0, u1, u2, u3, u4, o;
  u0.v = a0; u1.v = a1; u2.v = a2; u3.v = a3; u4.v = a4;
  #pragma unroll
  for (int e = 0; e < 8; ++e) {
    float f = bf2f(u0.h[e]) + bf2f(u1.h[e]) + bf2f(u2.h[e]) + bf2f(u3.h[e]) + bf2f(u4.h[e]);
    o.h[e] = f2bf(f);
  }
  return o.v;
}

// ---------------- fused: LN1 (+pos add, x save) for blocks < M; weight cvt above ----------------
constexpr int NQ = 3 * CD * CD, NP = CD * CD, N1 = HID * CD, N2 = CD * HID;
constexpr int CVT_BLOCKS = (NQ + NP + N1 + N2) / 512;  // 128 thr x 4 elems

__global__ __launch_bounds__(128) void ln_cvt_kernel(
    const float* __restrict__ xin, const float* __restrict__ pos,
    const float* __restrict__ g, const float* __restrict__ bta,
    float* __restrict__ x1out, u16* __restrict__ hout,
    const float* __restrict__ s0, u16* __restrict__ d0,
    const float* __restrict__ s1, u16* __restrict__ d1,
    const float* __restrict__ s2, u16* __restrict__ d2,
    const float* __restrict__ s3, u16* __restrict__ d3) {
  int t = threadIdx.x;
  if (blockIdx.x >= M) {
    int i = ((blockIdx.x - M) * 128 + t) * 4;
    const float* s; u16* d; int base;
    if (i < NQ)                { s = s0; d = d0; base = 0; }
    else if (i < NQ + NP)      { s = s1; d = d1; base = NQ; }
    else if (i < NQ + NP + N1) { s = s2; d = d2; base = NQ + NP; }
    else                       { s = s3; d = d3; base = NQ + NP + N1; }
    int j = i - base;
    float4 v = *(const float4*)(s + j);
    ushort4 o; o.x = f2bf(v.x); o.y = f2bf(v.y); o.z = f2bf(v.z); o.w = f2bf(v.w);
    *(ushort4*)(d + j) = o;
    return;
  }
  int row = blockIdx.x;
  int n = row % NT;
  const float* xr = xin + (size_t)row * CD;
  float v[3], s1v = 0.f, s2v = 0.f;
  #pragma unroll
  for (int j = 0; j < 3; ++j) {
    int c = t + j * 128;
    float x = xr[c] + pos[(size_t)n * CD + c];
    v[j] = x; s1v += x; s2v += x * x;
  }
  #pragma unroll
  for (int off = 32; off; off >>= 1) { s1v += __shfl_down(s1v, off); s2v += __shfl_down(s2v, off); }
  __shared__ float rbuf[4];
  __shared__ float stats[2];
  int lane = t & 63, wid = t >> 6;
  if (lane == 0) { rbuf[wid] = s1v; rbuf[2 + wid] = s2v; }
  __syncthreads();
  if (t == 0) {
    float a = rbuf[0] + rbuf[1], b2 = rbuf[2] + rbuf[3];
    float mu = a / CD;
    float var = b2 / CD - mu * mu;
    stats[0] = mu; stats[1] = rsqrtf(var + 1e-5f);
  }
  __syncthreads();
  float mu = stats[0], rs = stats[1];
  #pragma unroll
  for (int j = 0; j < 3; ++j) {
    int c = t + j * 128;
    float h = (v[j] - mu) * rs * g[c] + bta[c];
    hout[(size_t)row * CD + c] = f2bf(h);
    x1out[(size_t)row * CD + c] = v[j];
  }
}

// ---------------- plain layernorm (for LN2) ----------------
__global__ __launch_bounds__(128) void ln_kernel(
    const float* __restrict__ xin,
    const float* __restrict__ g, const float* __restrict__ bta,
    u16* __restrict__ hout) {
  int row = blockIdx.x;
  int t = threadIdx.x;
  const float* xr = xin + (size_t)row * CD;
  float v[3], s1 = 0.f, s2 = 0.f;
  #pragma unroll
  for (int j = 0; j < 3; ++j) {
    int c = t + j * 128;
    float x = xr[c];
    v[j] = x; s1 += x; s2 += x * x;
  }
  #pragma unroll
  for (int off = 32; off; off >>= 1) { s1 += __shfl_down(s1, off); s2 += __shfl_down(s2, off); }
  __shared__ float rbuf[4];
  __shared__ float stats[2];
  int lane = t & 63, wid = t >> 6;
  if (lane == 0) { rbuf[wid] = s1; rbuf[2 + wid] = s2; }
  __syncthreads();
  if (t == 0) {
    float a = rbuf[0] + rbuf[1], b2 = rbuf[2] + rbuf[3];
    float mu = a / CD;
    float var = b2 / CD - mu * mu;
    stats[0] = mu; stats[1] = rsqrtf(var + 1e-5f);
  }
  __syncthreads();
  float mu = stats[0], rs = stats[1];
  #pragma unroll
  for (int j = 0; j < 3; ++j) {
    int c = t + j * 128;
    hout[(size_t)row * CD + c] = f2bf((v[j] - mu) * rs * g[c] + bta[c]);
  }
}

// ---------------- bf16 GEMM: out[M,N] = A[M,K] @ W[N,K]^T ----------------
// EPI: 0 = qkv scatter (LDS-transposed coalesced stores)
//      2 = fc1 (bias + exact gelu -> bf16)
//      3 = fp32 out = acc + bias + res   (direct accumulate, no split-K)
// OSUM: A = o_part (5 bf16 slices summed during staging)
template <int EPI, bool OSUM>
__global__ __launch_bounds__(256) void gemm_bt(
    const u16* __restrict__ A, const u16* __restrict__ Wt, int K,
    const float* __restrict__ bias, const float* __restrict__ res,
    float* __restrict__ outf, u16* __restrict__ outb,
    u16* __restrict__ qout, u16* __restrict__ kout, u16* __restrict__ vtout) {
  __shared__ __align__(16) u16 As[64][72];
  __shared__ __align__(16) u16 Bs[64][72];
  int m0 = blockIdx.y * 64, n0 = blockIdx.x * 64;
  int t = threadIdx.x;
  int lane = t & 63, w = t >> 6, wm = w & 1, wn = w >> 1;
  int quad = lane >> 4, c16 = lane & 15;
  int lrow = t >> 2, lseg = t & 3;
  constexpr int SL = OSUM ? 5 : 1;
  const u16* ga[SL];
  #pragma unroll
  for (int s = 0; s < SL; ++s)
    ga[s] = A + (size_t)s * M * CD + (size_t)(m0 + lrow) * K + lseg * 8;
  const u16* gb = Wt + (size_t)(n0 + lrow) * K + lseg * 8;
  floatx4 acc[2][2] = {};
  uint4 av0[SL], av1[SL], bv0, bv1;
  #pragma unroll
  for (int s = 0; s < SL; ++s) { av0[s] = *(const uint4*)(ga[s]); av1[s] = *(const uint4*)(ga[s] + 32); }
  bv0 = *(const uint4*)(gb);
  bv1 = *(const uint4*)(gb + 32);
  for (int k0 = 0; k0 < K; k0 += 64) {
    __syncthreads();
    uint4 wa0, wa1;
    if (OSUM) {
      wa0 = sum5_bf(av0[0], av0[1], av0[2], av0[3], av0[4 % SL]);
      wa1 = sum5_bf(av1[0], av1[1], av1[2], av1[3], av1[4 % SL]);
    } else { wa0 = av0[0]; wa1 = av1[0]; }
    *(uint4*)&As[lrow][lseg * 8] = wa0;
    *(uint4*)&As[lrow][32 + lseg * 8] = wa1;
    *(uint4*)&Bs[lrow][lseg * 8] = bv0;
    *(uint4*)&Bs[lrow][32 + lseg * 8] = bv1;
    __syncthreads();
    if (k0 + 64 < K) {  // prefetch next K-tile; latency hides under MFMA below
      #pragma unroll
      for (int s = 0; s < SL; ++s) {
        av0[s] = *(const uint4*)(ga[s] + k0 + 64);
        av1[s] = *(const uint4*)(ga[s] + k0 + 96);
      }
      bv0 = *(const uint4*)(gb + k0 + 64);
      bv1 = *(const uint4*)(gb + k0 + 96);
    }
    #pragma unroll
    for (int ks = 0; ks < 2; ++ks) {
      short8 af[2], bf[2];
      #pragma unroll
      for (int mt = 0; mt < 2; ++mt) af[mt] = *(const short8*)&As[wm * 32 + mt * 16 + c16][ks * 32 + quad * 8];
      #pragma unroll
      for (int nt = 0; nt < 2; ++nt) bf[nt] = *(const short8*)&Bs[wn * 32 + nt * 16 + c16][ks * 32 + quad * 8];
      #pragma unroll
      for (int mt = 0; mt < 2; ++mt)
        #pragma unroll
        for (int nt = 0; nt < 2; ++nt)
          acc[mt][nt] = MFMA16(af[mt], bf[nt], acc[mt][nt]);
    }
  }
  if (EPI == 0) {
    // qkv scatter: stage tile in LDS (transposed for V), store coalesced.
    int s = n0 / 384;                 // 0=q 1=k 2=v
    int hh = (n0 % 384) / 64;
    int b_ = m0 / NT, nn0 = m0 % NT;
    __syncthreads();
    #pragma unroll
    for (int mt = 0; mt < 2; ++mt)
      #pragma unroll
      for (int nt = 0; nt < 2; ++nt)
        #pragma unroll
        for (int r = 0; r < 4; ++r) {
          int m_l = wm * 32 + mt * 16 + quad * 4 + r;
          int d_l = wn * 32 + nt * 16 + c16;
          u16 bv = f2bf(acc[mt][nt][r]);
          if (s < 2) As[m_l][d_l] = bv;
          else       As[d_l][m_l] = bv;
        }
    __syncthreads();
    int row = t >> 2, cs0 = (t & 3) * 16;
    uint4 va = *(const uint4*)&As[row][cs0];
    uint4 vb = *(const uint4*)&As[row][cs0 + 8];
    u16* dst;
    if (s == 0)      dst = qout  + ((size_t)(b_ * NH + hh) * NT + nn0 + row) * HD + cs0;
    else if (s == 1) dst = kout  + ((size_t)(b_ * NH + hh) * NT + nn0 + row) * HD + cs0;
    else             dst = vtout + ((size_t)(b_ * NH + hh) * HD + row) * NT + nn0 + cs0;
    *(uint4*)dst = va;
    *(uint4*)(dst + 8) = vb;
  } else {
    #pragma unroll
    for (int mt = 0; mt < 2; ++mt) {
      #pragma unroll
      for (int nt = 0; nt < 2; ++nt) {
        int rg0 = m0 + wm * 32 + mt * 16 + quad * 4;
        int cg = n0 + wn * 32 + nt * 16 + c16;
        #pragma unroll
        for (int r = 0; r < 4; ++r) {
          float v = acc[mt][nt][r];
          int m = rg0 + r;
          if (EPI == 2) {
            v += bias[cg];
            v = 0.5f * v * (1.0f + erff(v * 0.70710678118f));
            outb[(size_t)m * HID + cg] = f2bf(v);
          } else {
            outf[(size_t)m * CD + cg] = v + bias[cg] + res[(size_t)m * CD + cg];
          }
        }
      }
    }
  }
}

// ---------------- attention pass 1: partial (m, l) per column chunk ----------------
// Direct per-wave K reads from L2 (no LDS staging, no barriers in the loop):
// K/V working set (~7 MB across active bh) is L2-resident; barrier-free waves
// pipeline loads under MFMA via TLP. Swapped-operand QK^T keeps row stats cheap.
__global__ __launch_bounds__(256) void attn_pass1(
    const u16* __restrict__ qb, const u16* __restrict__ kb, float* __restrict__ ml) {
  int bh = blockIdx.y, chunk = blockIdx.z;
  int q0 = blockIdx.x * 64;
  int t = threadIdx.x, w = t >> 6, lane = t & 63, quad = lane >> 4, c16 = lane & 15;

  const u16* qp = qb + ((size_t)bh * NT + q0 + w * 16 + c16) * HD;
  short8 qf0 = *(const short8*)(qp + quad * 8);
  short8 qf1 = *(const short8*)(qp + 32 + quad * 8);
  const u16* kbase = kb + (size_t)bh * NT * HD;

  float m_i = -1e30f, l_i = 0.f;

  for (int ct = 0; ct < CTILES; ++ct) {
    int col0 = (chunk * CTILES + ct) * 64;
    floatx4 s_acc[4] = {};
    #pragma unroll
    for (int nt = 0; nt < 4; ++nt) {
      const u16* kp = kbase + (size_t)(col0 + nt * 16 + c16) * HD + quad * 8;
      s_acc[nt] = MFMA16(*(const short8*)(kp), qf0, s_acc[nt]);
      s_acc[nt] = MFMA16(*(const short8*)(kp + 32), qf1, s_acc[nt]);
    }
    float rm = -1e30f;
    #pragma unroll
    for (int nt = 0; nt < 4; ++nt)
      #pragma unroll
      for (int r = 0; r < 4; ++r) rm = fmaxf(rm, s_acc[nt][r]);
    rm *= SCALE;
    rm = fmaxf(rm, __shfl_xor(rm, 16));
    rm = fmaxf(rm, __shfl_xor(rm, 32));
    float nm = fmaxf(m_i, rm);
    float ps = 0.f;
    #pragma unroll
    for (int nt = 0; nt < 4; ++nt)
      #pragma unroll
      for (int r = 0; r < 4; ++r) ps += __expf(s_acc[nt][r] * SCALE - nm);
    ps += __shfl_xor(ps, 16);
    ps += __shfl_xor(ps, 32);
    l_i = l_i * __expf(m_i - nm) + ps;
    m_i = nm;
  }
  if (quad == 0) {
    int row = q0 + w * 16 + c16;
    float* p = ml + ((size_t)(bh * NT + row) * CS + chunk) * 2;
    p[0] = m_i; p[1] = l_i;
  }
}

// ---------------- attention pass 2: write attn, bf16 partial O per chunk ----------------
// Direct per-wave K/V reads (no K/V LDS staging, no loop barriers). Plds kept:
// it is per-wave private (P fragment relayout), so no barriers needed for it.
__global__ __launch_bounds__(256) void attn_pass2(
    const u16* __restrict__ qb, const u16* __restrict__ kb, const u16* __restrict__ vtb,
    const float* __restrict__ ml, float* __restrict__ attn_out, u16* __restrict__ o_part) {
  __shared__ __align__(16) u16 Plds[4][16][72];
  __shared__ float mfin[64], rlfin[64];
  int bh = blockIdx.y, chunk = blockIdx.z;
  int b = bh / NH, hh = bh % NH;
  int q0 = blockIdx.x * 64;
  int t = threadIdx.x, w = t >> 6, lane = t & 63, quad = lane >> 4, c16 = lane & 15;

  if (t < 64) {
    const float* p = ml + (size_t)(bh * NT + q0 + t) * CS * 2;
    float mm = -1e30f;
    #pragma unroll
    for (int c = 0; c < CS; ++c) mm = fmaxf(mm, p[c * 2]);
    float ll = 0.f;
    #pragma unroll
    for (int c = 0; c < CS; ++c) ll += p[c * 2 + 1] * __expf(p[c * 2] - mm);
    mfin[t] = mm; rlfin[t] = 1.0f / ll;
  }
  __syncthreads();
  float m_i[4], rl[4];
  #pragma unroll
  for (int r = 0; r < 4; ++r) {
    int rr = w * 16 + quad * 4 + r;
    m_i[r] = mfin[rr]; rl[r] = rlfin[rr];
  }

  const u16* qp = qb + ((size_t)bh * NT + q0 + w * 16 + c16) * HD;
  short8 qf0 = *(const short8*)(qp + quad * 8);
  short8 qf1 = *(const short8*)(qp + 32 + quad * 8);
  const u16* kbase = kb + (size_t)bh * NT * HD;
  const u16* vbase = vtb + (size_t)bh * HD * NT;

  floatx4 o_acc[4] = {};
  float* attn_bh = attn_out + (size_t)bh * NT * NT;
  for (int ct = 0; ct < CTILES; ++ct) {
    int col0 = (chunk * CTILES + ct) * 64;
    floatx4 s_acc[4] = {};
    #pragma unroll
    for (int nt = 0; nt < 4; ++nt) {
      const u16* kp = kbase + (size_t)(col0 + nt * 16 + c16) * HD + quad * 8;
      s_acc[nt] = MFMA16(qf0, *(const short8*)(kp), s_acc[nt]);
      s_acc[nt] = MFMA16(qf1, *(const short8*)(kp + 32), s_acc[nt]);
    }
    #pragma unroll
    for (int nt = 0; nt < 4; ++nt) {
      #pragma unroll
      for (int r = 0; r < 4; ++r) {
        float p = __expf(s_acc[nt][r] * SCALE - m_i[r]) * rl[r];
        __builtin_nontemporal_store(
            p, &attn_bh[(size_t)(q0 + w * 16 + quad * 4 + r) * NT + col0 + nt * 16 + c16]);
        Plds[w][quad * 4 + r][nt * 16 + c16] = f2bf(p);
      }
    }
    #pragma unroll
    for (int ks = 0; ks < 2; ++ks) {
      short8 pa = *(const short8*)&Plds[w][c16][ks * 32 + quad * 8];
      #pragma unroll
      for (int dt = 0; dt < 4; ++dt) {
        const u16* vp = vbase + (size_t)(dt * 16 + c16) * NT + col0 + ks * 32 + quad * 8;
        o_acc[dt] = MFMA16(pa, *(const short8*)(vp), o_acc[dt]);
      }
    }
  }
  #pragma unroll
  for (int dt = 0; dt < 4; ++dt) {
    #pragma unroll
    for (int r = 0; r < 4; ++r) {
      int m = b * NT + q0 + w * 16 + quad * 4 + r;
      int cc = hh * 64 + dt * 16 + c16;
      o_part[((size_t)chunk * M + m) * CD + cc] = f2bf(o_acc[dt][r]);
    }
  }
}

// ---------------- launch ----------------
extern "C" void kernel_launch(void* const* d_in, const int* in_sizes, int n_in,
                              void* d_out, int out_size, void* d_ws, size_t ws_size,
                              hipStream_t stream) {
  const float* x      = (const float*)d_in[0];
  const float* pos    = (const float*)d_in[1];
  const float* ln1_g  = (const float*)d_in[2];
  const float* ln1_b  = (const float*)d_in[3];
  const float* w_qkv  = (const float*)d_in[4];
  const float* w_proj = (const float*)d_in[5];
  const float* b_proj = (const float*)d_in[6];
  const float* ln2_g  = (const float*)d_in[7];
  const float* ln2_b  = (const float*)d_in[8];
  const float* w_fc1  = (const float*)d_in[9];
  const float* b_fc1  = (const float*)d_in[10];
  const float* w_fc2  = (const float*)d_in[11];
  const float* b_fc2  = (const float*)d_in[12];

  float* out      = (float*)d_out;
  float* attn_out = out + (size_t)M * CD;

  char* ws = (char*)d_ws;
  size_t o = 0;
  auto carve = [&](size_t bytes) { char* p = ws + o; o += bytes; return p; };
  float* x1    = (float*)carve((size_t)M * CD * 4);
  u16* h1      = (u16*)carve((size_t)M * CD * 2);
  u16* wqkv_b  = (u16*)carve((size_t)3 * CD * CD * 2);
  u16* wproj_b = (u16*)carve((size_t)CD * CD * 2);
  u16* wfc1_b  = (u16*)carve((size_t)HID * CD * 2);
  u16* wfc2_b  = (u16*)carve((size_t)CD * HID * 2);
  u16* q_bf    = (u16*)carve((size_t)BB * NH * NT * HD * 2);
  u16* k_bf    = (u16*)carve((size_t)BB * NH * NT * HD * 2);
  u16* vt_bf   = (u16*)carve((size_t)BB * NH * NT * HD * 2);
  float* x2    = (float*)carve((size_t)M * CD * 4);
  u16* h2      = (u16*)carve((size_t)M * CD * 2);
  u16* g_bf    = (u16*)carve((size_t)M * HID * 2);
  float* ml    = (float*)carve((size_t)NH * BB * NT * CS * 2 * 4);
  u16* o_part  = (u16*)carve((size_t)CS * M * CD * 2);
  (void)ws_size; (void)in_sizes; (void)n_in; (void)out_size;

  // LN1 (+pos, x1 save) and all weight converts in ONE launch
  ln_cvt_kernel<<<M + CVT_BLOCKS, 128, 0, stream>>>(
      x, pos, ln1_g, ln1_b, x1, h1,
      w_qkv, wqkv_b, w_proj, wproj_b, w_fc1, wfc1_b, w_fc2, wfc2_b);

  // qkv = h1 @ w_qkv^T, scatter to q/k/vT (coalesced via LDS transpose)
  gemm_bt<0, false><<<dim3((3 * CD) / 64, M / 64), 256, 0, stream>>>(
      h1, wqkv_b, CD, nullptr, nullptr, nullptr, nullptr, q_bf, k_bf, vt_bf);

  // attention (column-chunked two-pass, direct L2 K/V reads, barrier-free loops)
  attn_pass1<<<dim3(NT / 64, BB * NH, CS), 256, 0, stream>>>(q_bf, k_bf, ml);
  attn_pass2<<<dim3(NT / 64, BB * NH, CS), 256, 0, stream>>>(q_bf, k_bf, vt_bf, ml, attn_out, o_part);

  // x2 = x1 + b_proj + (sum o_part) @ w_proj^T   (osum fused into A-staging)
  gemm_bt<3, true><<<dim3(CD / 64, M / 64), 256, 0, stream>>>(
      o_part, wproj_b, CD, b_proj, x1, x2, nullptr, nullptr, nullptr, nullptr);
  ln_kernel<<<M, 128, 0, stream>>>(x2, ln2_g, ln2_b, h2);

  // g = gelu(h2 @ w_fc1^T + b_fc1)
  gemm_bt<2, false><<<dim3(HID / 64, M / 64), 256, 0, stream>>>(
      h2, wfc1_b, CD, b_fc1, nullptr, nullptr, g_bf, nullptr, nullptr, nullptr);

  // out = x2 + b_fc2 + g @ w_fc2^T (direct K=1536, fused residual)
  gemm_bt<3, false><<<dim3(CD / 64, M / 64), 256, 0, stream>>>(
      g_bf, wfc2_b, HID, b_fc2, x2, out, nullptr, nullptr, nullptr, nullptr);
}

// Round 10
// 399.164 us; speedup vs baseline: 1.2430x; 1.2430x over previous
//
#include <hip/hip_runtime.h>
#include <math.h>

typedef unsigned short u16;
typedef unsigned int   u32;
typedef __attribute__((ext_vector_type(8))) short short8;
typedef __attribute__((ext_vector_type(4))) float floatx4;
typedef __attribute__((ext_vector_type(4))) unsigned short u16x4;

#define MFMA16(a,b,c) __builtin_amdgcn_mfma_f32_16x16x32_bf16((a),(b),(c),0,0,0)

constexpr int BB  = 2;
constexpr int NT  = 2240;
constexpr int CD  = 384;
constexpr int NH  = 6;
constexpr int HD  = 64;
constexpr int HID = 1536;
constexpr int M   = BB * NT;          // 4480
constexpr int CS  = 5;                // attn column chunks
constexpr int CTILES = NT / 64 / CS;  // 7 col-tiles per chunk
constexpr float SCALE = 0.125f;

__device__ inline u16 f2bf(float f) {
  u32 u = __float_as_uint(f);
  u = (u + 0x7fffu + ((u >> 16) & 1u)) >> 16;
  return (u16)u;
}
__device__ inline float bf2f(u16 b) { return __uint_as_float(((u32)b) << 16); }

__device__ inline uint4 sum5_bf(uint4 a0, uint4 a1, uint4 a2, uint4 a3, uint4 a4) {
  union U { uint4 v; u16 h[8]; };
  U u0, u1, u2, u3, u4, o;
  u0.v = a0; u1.v = a1; u2.v = a2; u3.v = a3; u4.v = a4;
  #pragma unroll
  for (int e = 0; e < 8; ++e) {
    float f = bf2f(u0.h[e]) + bf2f(u1.h[e]) + bf2f(u2.h[e]) + bf2f(u3.h[e]) + bf2f(u4.h[e]);
    o.h[e] = f2bf(f);
  }
  return o.v;
}

// ---------------- fused: LN1 (+pos add, x save) for blocks < M; weight cvt above ----------------
constexpr int NQ = 3 * CD * CD, NP = CD * CD, N1 = HID * CD, N2 = CD * HID;
constexpr int CVT_BLOCKS = (NQ + NP + N1 + N2) / 512;  // 128 thr x 4 elems

__global__ __launch_bounds__(128) void ln_cvt_kernel(
    const float* __restrict__ xin, const float* __restrict__ pos,
    const float* __restrict__ g, const float* __restrict__ bta,
    float* __restrict__ x1out, u16* __restrict__ hout,
    const float* __restrict__ s0, u16* __restrict__ d0,
    const float* __restrict__ s1, u16* __restrict__ d1,
    const float* __restrict__ s2, u16* __restrict__ d2,
    const float* __restrict__ s3, u16* __restrict__ d3) {
  int t = threadIdx.x;
  if (blockIdx.x >= M) {
    int i = ((blockIdx.x - M) * 128 + t) * 4;
    const float* s; u16* d; int base;
    if (i < NQ)                { s = s0; d = d0; base = 0; }
    else if (i < NQ + NP)      { s = s1; d = d1; base = NQ; }
    else if (i < NQ + NP + N1) { s = s2; d = d2; base = NQ + NP; }
    else                       { s = s3; d = d3; base = NQ + NP + N1; }
    int j = i - base;
    float4 v = *(const float4*)(s + j);
    ushort4 o; o.x = f2bf(v.x); o.y = f2bf(v.y); o.z = f2bf(v.z); o.w = f2bf(v.w);
    *(ushort4*)(d + j) = o;
    return;
  }
  int row = blockIdx.x;
  int n = row % NT;
  const float* xr = xin + (size_t)row * CD;
  float v[3], s1v = 0.f, s2v = 0.f;
  #pragma unroll
  for (int j = 0; j < 3; ++j) {
    int c = t + j * 128;
    float x = xr[c] + pos[(size_t)n * CD + c];
    v[j] = x; s1v += x; s2v += x * x;
  }
  #pragma unroll
  for (int off = 32; off; off >>= 1) { s1v += __shfl_down(s1v, off); s2v += __shfl_down(s2v, off); }
  __shared__ float rbuf[4];
  __shared__ float stats[2];
  int lane = t & 63, wid = t >> 6;
  if (lane == 0) { rbuf[wid] = s1v; rbuf[2 + wid] = s2v; }
  __syncthreads();
  if (t == 0) {
    float a = rbuf[0] + rbuf[1], b2 = rbuf[2] + rbuf[3];
    float mu = a / CD;
    float var = b2 / CD - mu * mu;
    stats[0] = mu; stats[1] = rsqrtf(var + 1e-5f);
  }
  __syncthreads();
  float mu = stats[0], rs = stats[1];
  #pragma unroll
  for (int j = 0; j < 3; ++j) {
    int c = t + j * 128;
    float h = (v[j] - mu) * rs * g[c] + bta[c];
    hout[(size_t)row * CD + c] = f2bf(h);
    x1out[(size_t)row * CD + c] = v[j];
  }
}

// ---------------- plain layernorm (for LN2) ----------------
__global__ __launch_bounds__(128) void ln_kernel(
    const float* __restrict__ xin,
    const float* __restrict__ g, const float* __restrict__ bta,
    u16* __restrict__ hout) {
  int row = blockIdx.x;
  int t = threadIdx.x;
  const float* xr = xin + (size_t)row * CD;
  float v[3], s1 = 0.f, s2 = 0.f;
  #pragma unroll
  for (int j = 0; j < 3; ++j) {
    int c = t + j * 128;
    float x = xr[c];
    v[j] = x; s1 += x; s2 += x * x;
  }
  #pragma unroll
  for (int off = 32; off; off >>= 1) { s1 += __shfl_down(s1, off); s2 += __shfl_down(s2, off); }
  __shared__ float rbuf[4];
  __shared__ float stats[2];
  int lane = t & 63, wid = t >> 6;
  if (lane == 0) { rbuf[wid] = s1; rbuf[2 + wid] = s2; }
  __syncthreads();
  if (t == 0) {
    float a = rbuf[0] + rbuf[1], b2 = rbuf[2] + rbuf[3];
    float mu = a / CD;
    float var = b2 / CD - mu * mu;
    stats[0] = mu; stats[1] = rsqrtf(var + 1e-5f);
  }
  __syncthreads();
  float mu = stats[0], rs = stats[1];
  #pragma unroll
  for (int j = 0; j < 3; ++j) {
    int c = t + j * 128;
    hout[(size_t)row * CD + c] = f2bf((v[j] - mu) * rs * g[c] + bta[c]);
  }
}

// ---------------- bf16 GEMM: out[M,N] = A[M,K] @ W[N,K]^T ----------------
// EPI: 0 = qkv scatter (LDS-transposed coalesced stores)
//      2 = fc1 (bias + exact gelu -> bf16)
//      3 = fp32 out = acc + bias + res   (direct accumulate, no split-K)
// OSUM: A = o_part (5 bf16 slices summed during staging)
template <int EPI, bool OSUM>
__global__ __launch_bounds__(256) void gemm_bt(
    const u16* __restrict__ A, const u16* __restrict__ Wt, int K,
    const float* __restrict__ bias, const float* __restrict__ res,
    float* __restrict__ outf, u16* __restrict__ outb,
    u16* __restrict__ qout, u16* __restrict__ kout, u16* __restrict__ vtout) {
  __shared__ __align__(16) u16 As[64][72];
  __shared__ __align__(16) u16 Bs[64][72];
  int m0 = blockIdx.y * 64, n0 = blockIdx.x * 64;
  int t = threadIdx.x;
  int lane = t & 63, w = t >> 6, wm = w & 1, wn = w >> 1;
  int quad = lane >> 4, c16 = lane & 15;
  int lrow = t >> 2, lseg = t & 3;
  constexpr int SL = OSUM ? 5 : 1;
  const u16* ga[SL];
  #pragma unroll
  for (int s = 0; s < SL; ++s)
    ga[s] = A + (size_t)s * M * CD + (size_t)(m0 + lrow) * K + lseg * 8;
  const u16* gb = Wt + (size_t)(n0 + lrow) * K + lseg * 8;
  floatx4 acc[2][2] = {};
  uint4 av0[SL], av1[SL], bv0, bv1;
  #pragma unroll
  for (int s = 0; s < SL; ++s) { av0[s] = *(const uint4*)(ga[s]); av1[s] = *(const uint4*)(ga[s] + 32); }
  bv0 = *(const uint4*)(gb);
  bv1 = *(const uint4*)(gb + 32);
  for (int k0 = 0; k0 < K; k0 += 64) {
    __syncthreads();
    uint4 wa0, wa1;
    if (OSUM) {
      wa0 = sum5_bf(av0[0], av0[1], av0[2], av0[3], av0[4 % SL]);
      wa1 = sum5_bf(av1[0], av1[1], av1[2], av1[3], av1[4 % SL]);
    } else { wa0 = av0[0]; wa1 = av1[0]; }
    *(uint4*)&As[lrow][lseg * 8] = wa0;
    *(uint4*)&As[lrow][32 + lseg * 8] = wa1;
    *(uint4*)&Bs[lrow][lseg * 8] = bv0;
    *(uint4*)&Bs[lrow][32 + lseg * 8] = bv1;
    __syncthreads();
    if (k0 + 64 < K) {  // prefetch next K-tile; latency hides under MFMA below
      #pragma unroll
      for (int s = 0; s < SL; ++s) {
        av0[s] = *(const uint4*)(ga[s] + k0 + 64);
        av1[s] = *(const uint4*)(ga[s] + k0 + 96);
      }
      bv0 = *(const uint4*)(gb + k0 + 64);
      bv1 = *(const uint4*)(gb + k0 + 96);
    }
    #pragma unroll
    for (int ks = 0; ks < 2; ++ks) {
      short8 af[2], bf[2];
      #pragma unroll
      for (int mt = 0; mt < 2; ++mt) af[mt] = *(const short8*)&As[wm * 32 + mt * 16 + c16][ks * 32 + quad * 8];
      #pragma unroll
      for (int nt = 0; nt < 2; ++nt) bf[nt] = *(const short8*)&Bs[wn * 32 + nt * 16 + c16][ks * 32 + quad * 8];
      #pragma unroll
      for (int mt = 0; mt < 2; ++mt)
        #pragma unroll
        for (int nt = 0; nt < 2; ++nt)
          acc[mt][nt] = MFMA16(af[mt], bf[nt], acc[mt][nt]);
    }
  }
  if (EPI == 0) {
    // qkv scatter: stage tile in LDS (transposed for V), store coalesced.
    int s = n0 / 384;                 // 0=q 1=k 2=v
    int hh = (n0 % 384) / 64;
    int b_ = m0 / NT, nn0 = m0 % NT;
    __syncthreads();
    #pragma unroll
    for (int mt = 0; mt < 2; ++mt)
      #pragma unroll
      for (int nt = 0; nt < 2; ++nt)
        #pragma unroll
        for (int r = 0; r < 4; ++r) {
          int m_l = wm * 32 + mt * 16 + quad * 4 + r;
          int d_l = wn * 32 + nt * 16 + c16;
          u16 bv = f2bf(acc[mt][nt][r]);
          if (s < 2) As[m_l][d_l] = bv;
          else       As[d_l][m_l] = bv;
        }
    __syncthreads();
    int row = t >> 2, cs0 = (t & 3) * 16;
    uint4 va = *(const uint4*)&As[row][cs0];
    uint4 vb = *(const uint4*)&As[row][cs0 + 8];
    u16* dst;
    if (s == 0)      dst = qout  + ((size_t)(b_ * NH + hh) * NT + nn0 + row) * HD + cs0;
    else if (s == 1) dst = kout  + ((size_t)(b_ * NH + hh) * NT + nn0 + row) * HD + cs0;
    else             dst = vtout + ((size_t)(b_ * NH + hh) * HD + row) * NT + nn0 + cs0;
    *(uint4*)dst = va;
    *(uint4*)(dst + 8) = vb;
  } else {
    #pragma unroll
    for (int mt = 0; mt < 2; ++mt) {
      #pragma unroll
      for (int nt = 0; nt < 2; ++nt) {
        int rg0 = m0 + wm * 32 + mt * 16 + quad * 4;
        int cg = n0 + wn * 32 + nt * 16 + c16;
        #pragma unroll
        for (int r = 0; r < 4; ++r) {
          float v = acc[mt][nt][r];
          int m = rg0 + r;
          if (EPI == 2) {
            v += bias[cg];
            v = 0.5f * v * (1.0f + erff(v * 0.70710678118f));
            outb[(size_t)m * HID + cg] = f2bf(v);
          } else {
            outf[(size_t)m * CD + cg] = v + bias[cg] + res[(size_t)m * CD + cg];
          }
        }
      }
    }
  }
}

// ---------------- attention pass 1: partial (m, l) per column chunk ----------------
// swapped-operand QK^T: mfma(K, Q) -> each lane holds 16 scores of ONE q-row.
__global__ __launch_bounds__(256) void attn_pass1(
    const u16* __restrict__ qb, const u16* __restrict__ kb, float* __restrict__ ml) {
  __shared__ __align__(16) u16 Ks[64][72];
  int bh = blockIdx.y, chunk = blockIdx.z;
  int q0 = blockIdx.x * 64;
  int t = threadIdx.x, w = t >> 6, lane = t & 63, quad = lane >> 4, c16 = lane & 15;
  int lrow = t >> 2, lseg = t & 3;

  const u16* qp = qb + ((size_t)bh * NT + q0 + w * 16 + c16) * HD;
  short8 qf0 = *(const short8*)(qp + quad * 8);
  short8 qf1 = *(const short8*)(qp + 32 + quad * 8);
  const u16* kbase = kb + (size_t)bh * NT * HD;

  float m_i = -1e30f, l_i = 0.f;

  const u16* kg = kbase + (size_t)(chunk * CTILES * 64 + lrow) * HD + lseg * 8;
  uint4 kv0 = *(const uint4*)kg;
  uint4 kv1 = *(const uint4*)(kg + 32);

  for (int ct = 0; ct < CTILES; ++ct) {
    __syncthreads();
    *(uint4*)&Ks[lrow][lseg * 8] = kv0;
    *(uint4*)&Ks[lrow][32 + lseg * 8] = kv1;
    __syncthreads();
    if (ct + 1 < CTILES) {
      const u16* kn = kbase + (size_t)((chunk * CTILES + ct + 1) * 64 + lrow) * HD + lseg * 8;
      kv0 = *(const uint4*)kn;
      kv1 = *(const uint4*)(kn + 32);
    }
    floatx4 s_acc[4] = {};
    #pragma unroll
    for (int nt = 0; nt < 4; ++nt) {
      const u16* kp = &Ks[nt * 16 + c16][quad * 8];
      s_acc[nt] = MFMA16(*(const short8*)(kp), qf0, s_acc[nt]);
      s_acc[nt] = MFMA16(*(const short8*)(kp + 32), qf1, s_acc[nt]);
    }
    float rm = -1e30f;
    #pragma unroll
    for (int nt = 0; nt < 4; ++nt)
      #pragma unroll
      for (int r = 0; r < 4; ++r) rm = fmaxf(rm, s_acc[nt][r]);
    rm *= SCALE;
    rm = fmaxf(rm, __shfl_xor(rm, 16));
    rm = fmaxf(rm, __shfl_xor(rm, 32));
    float nm = fmaxf(m_i, rm);
    float ps = 0.f;
    #pragma unroll
    for (int nt = 0; nt < 4; ++nt)
      #pragma unroll
      for (int r = 0; r < 4; ++r) ps += __expf(s_acc[nt][r] * SCALE - nm);
    ps += __shfl_xor(ps, 16);
    ps += __shfl_xor(ps, 32);
    l_i = l_i * __expf(m_i - nm) + ps;
    m_i = nm;
  }
  if (quad == 0) {
    int row = q0 + w * 16 + c16;
    float* p = ml + ((size_t)(bh * NT + row) * CS + chunk) * 2;
    p[0] = m_i; p[1] = l_i;
  }
}

// ---------------- attention pass 2: write attn, bf16 partial O per chunk ----------------
// Swapped-operand QK^T AND PV (same dot products, bit-identical results):
// each lane owns one q-row, so r=0..3 are CONSECUTIVE columns -> attn writes are
// 4 nontemporal dwordx4 (was 16 dwords), Plds writes are 4 ds_write_b64 (was 16 b16),
// o_part writes are 4x8B (was 16 b16). PV read path unchanged. K/V LDS staging kept
// (R8 measured: removing it costs +86us).
__global__ __launch_bounds__(256) void attn_pass2(
    const u16* __restrict__ qb, const u16* __restrict__ kb, const u16* __restrict__ vtb,
    const float* __restrict__ ml, float* __restrict__ attn_out, u16* __restrict__ o_part) {
  __shared__ __align__(16) u16 Ks[64][72];
  __shared__ __align__(16) u16 Vs[64][72];
  __shared__ __align__(16) u16 Plds[4][16][72];
  __shared__ float mfin[64], rlfin[64];
  int bh = blockIdx.y, chunk = blockIdx.z;
  int b = bh / NH, hh = bh % NH;
  int q0 = blockIdx.x * 64;
  int t = threadIdx.x, w = t >> 6, lane = t & 63, quad = lane >> 4, c16 = lane & 15;
  int lrow = t >> 2, lseg = t & 3;

  const u16* kbase = kb + (size_t)bh * NT * HD;
  const u16* vbase = vtb + (size_t)bh * HD * NT;

  // issue tile-0 loads first so latency hides under the ml-combine phase
  int col00 = chunk * CTILES * 64;
  const u16* kg = kbase + (size_t)(col00 + lrow) * HD + lseg * 8;
  const u16* vg = vbase + (size_t)lrow * NT + col00 + lseg * 8;
  uint4 kv0 = *(const uint4*)kg;
  uint4 kv1 = *(const uint4*)(kg + 32);
  uint4 vv0 = *(const uint4*)vg;
  uint4 vv1 = *(const uint4*)(vg + 32);

  if (t < 64) {
    const float* p = ml + (size_t)(bh * NT + q0 + t) * CS * 2;
    float mm = -1e30f;
    #pragma unroll
    for (int c = 0; c < CS; ++c) mm = fmaxf(mm, p[c * 2]);
    float ll = 0.f;
    #pragma unroll
    for (int c = 0; c < CS; ++c) ll += p[c * 2 + 1] * __expf(p[c * 2] - mm);
    mfin[t] = mm; rlfin[t] = 1.0f / ll;
  }
  __syncthreads();
  // swapped layout: each lane owns q-row w*16+c16 -> scalar (m, 1/l)
  float m_i = mfin[w * 16 + c16];
  float rl  = rlfin[w * 16 + c16];

  const u16* qp = qb + ((size_t)bh * NT + q0 + w * 16 + c16) * HD;
  short8 qf0 = *(const short8*)(qp + quad * 8);
  short8 qf1 = *(const short8*)(qp + 32 + quad * 8);

  int qrow = q0 + w * 16 + c16;
  floatx4 o_acc[4] = {};
  float* attn_bh = attn_out + (size_t)bh * NT * NT;
  for (int ct = 0; ct < CTILES; ++ct) {
    int col0 = (chunk * CTILES + ct) * 64;
    __syncthreads();
    *(uint4*)&Ks[lrow][lseg * 8] = kv0;
    *(uint4*)&Ks[lrow][32 + lseg * 8] = kv1;
    *(uint4*)&Vs[lrow][lseg * 8] = vv0;
    *(uint4*)&Vs[lrow][32 + lseg * 8] = vv1;
    __syncthreads();
    if (ct + 1 < CTILES) {
      int coln = col0 + 64;
      const u16* kn = kbase + (size_t)(coln + lrow) * HD + lseg * 8;
      const u16* vn = vbase + (size_t)lrow * NT + coln + lseg * 8;
      kv0 = *(const uint4*)kn;
      kv1 = *(const uint4*)(kn + 32);
      vv0 = *(const uint4*)vn;
      vv1 = *(const uint4*)(vn + 32);
    }
    // swapped QK^T: s_acc[nt][r] = S[qrow = w*16+c16][kcol = nt*16 + quad*4 + r]
    floatx4 s_acc[4] = {};
    #pragma unroll
    for (int nt = 0; nt < 4; ++nt) {
      const u16* kp = &Ks[nt * 16 + c16][quad * 8];
      s_acc[nt] = MFMA16(*(const short8*)(kp), qf0, s_acc[nt]);
      s_acc[nt] = MFMA16(*(const short8*)(kp + 32), qf1, s_acc[nt]);
    }
    #pragma unroll
    for (int nt = 0; nt < 4; ++nt) {
      floatx4 pv;
      u16x4 ph;
      #pragma unroll
      for (int r = 0; r < 4; ++r) {
        float p = __expf(s_acc[nt][r] * SCALE - m_i) * rl;
        pv[r] = p;
        ph[r] = f2bf(p);
      }
      __builtin_nontemporal_store(
          pv, (floatx4*)&attn_bh[(size_t)qrow * NT + col0 + nt * 16 + quad * 4]);
      *(u16x4*)&Plds[w][c16][nt * 16 + quad * 4] = ph;
    }
    // PV (swapped: A=V^T, B=P): o_acc[dt][r] = O[qrow][d = dt*16 + quad*4 + r]
    #pragma unroll
    for (int ks = 0; ks < 2; ++ks) {
      short8 pa = *(const short8*)&Plds[w][c16][ks * 32 + quad * 8];
      #pragma unroll
      for (int dt = 0; dt < 4; ++dt) {
        short8 vb = *(const short8*)&Vs[dt * 16 + c16][ks * 32 + quad * 8];
        o_acc[dt] = MFMA16(vb, pa, o_acc[dt]);
      }
    }
  }
  int m = b * NT + qrow;
  #pragma unroll
  for (int dt = 0; dt < 4; ++dt) {
    u16x4 oh;
    #pragma unroll
    for (int r = 0; r < 4; ++r) oh[r] = f2bf(o_acc[dt][r]);
    *(u16x4*)&o_part[((size_t)chunk * M + m) * CD + hh * 64 + dt * 16 + quad * 4] = oh;
  }
}

// ---------------- launch ----------------
extern "C" void kernel_launch(void* const* d_in, const int* in_sizes, int n_in,
                              void* d_out, int out_size, void* d_ws, size_t ws_size,
                              hipStream_t stream) {
  const float* x      = (const float*)d_in[0];
  const float* pos    = (const float*)d_in[1];
  const float* ln1_g  = (const float*)d_in[2];
  const float* ln1_b  = (const float*)d_in[3];
  const float* w_qkv  = (const float*)d_in[4];
  const float* w_proj = (const float*)d_in[5];
  const float* b_proj = (const float*)d_in[6];
  const float* ln2_g  = (const float*)d_in[7];
  const float* ln2_b  = (const float*)d_in[8];
  const float* w_fc1  = (const float*)d_in[9];
  const float* b_fc1  = (const float*)d_in[10];
  const float* w_fc2  = (const float*)d_in[11];
  const float* b_fc2  = (const float*)d_in[12];

  float* out      = (float*)d_out;
  float* attn_out = out + (size_t)M * CD;

  char* ws = (char*)d_ws;
  size_t o = 0;
  auto carve = [&](size_t bytes) { char* p = ws + o; o += bytes; return p; };
  float* x1    = (float*)carve((size_t)M * CD * 4);
  u16* h1      = (u16*)carve((size_t)M * CD * 2);
  u16* wqkv_b  = (u16*)carve((size_t)3 * CD * CD * 2);
  u16* wproj_b = (u16*)carve((size_t)CD * CD * 2);
  u16* wfc1_b  = (u16*)carve((size_t)HID * CD * 2);
  u16* wfc2_b  = (u16*)carve((size_t)CD * HID * 2);
  u16* q_bf    = (u16*)carve((size_t)BB * NH * NT * HD * 2);
  u16* k_bf    = (u16*)carve((size_t)BB * NH * NT * HD * 2);
  u16* vt_bf   = (u16*)carve((size_t)BB * NH * NT * HD * 2);
  float* x2    = (float*)carve((size_t)M * CD * 4);
  u16* h2      = (u16*)carve((size_t)M * CD * 2);
  u16* g_bf    = (u16*)carve((size_t)M * HID * 2);
  float* ml    = (float*)carve((size_t)NH * BB * NT * CS * 2 * 4);
  u16* o_part  = (u16*)carve((size_t)CS * M * CD * 2);
  (void)ws_size; (void)in_sizes; (void)n_in; (void)out_size;

  // LN1 (+pos, x1 save) and all weight converts in ONE launch
  ln_cvt_kernel<<<M + CVT_BLOCKS, 128, 0, stream>>>(
      x, pos, ln1_g, ln1_b, x1, h1,
      w_qkv, wqkv_b, w_proj, wproj_b, w_fc1, wfc1_b, w_fc2, wfc2_b);

  // qkv = h1 @ w_qkv^T, scatter to q/k/vT (coalesced via LDS transpose)
  gemm_bt<0, false><<<dim3((3 * CD) / 64, M / 64), 256, 0, stream>>>(
      h1, wqkv_b, CD, nullptr, nullptr, nullptr, nullptr, q_bf, k_bf, vt_bf);

  // attention (column-chunked two-pass, LDS-staged K/V tiles, prefetch pipelined)
  attn_pass1<<<dim3(NT / 64, BB * NH, CS), 256, 0, stream>>>(q_bf, k_bf, ml);
  attn_pass2<<<dim3(NT / 64, BB * NH, CS), 256, 0, stream>>>(q_bf, k_bf, vt_bf, ml, attn_out, o_part);

  // x2 = x1 + b_proj + (sum o_part) @ w_proj^T   (osum fused into A-staging)
  gemm_bt<3, true><<<dim3(CD / 64, M / 64), 256, 0, stream>>>(
      o_part, wproj_b, CD, b_proj, x1, x2, nullptr, nullptr, nullptr, nullptr);
  ln_kernel<<<M, 128, 0, stream>>>(x2, ln2_g, ln2_b, h2);

  // g = gelu(h2 @ w_fc1^T + b_fc1)
  gemm_bt<2, false><<<dim3(HID / 64, M / 64), 256, 0, stream>>>(
      h2, wfc1_b, CD, b_fc1, nullptr, nullptr, g_bf, nullptr, nullptr, nullptr);

  // out = x2 + b_fc2 + g @ w_fc2^T (direct K=1536, fused residual)
  gemm_bt<3, false><<<dim3(CD / 64, M / 64), 256, 0, stream>>>(
      g_bf, wfc2_b, HID, b_fc2, x2, out, nullptr, nullptr, nullptr, nullptr);
}

// Round 11
// 398.620 us; speedup vs baseline: 1.2447x; 1.0014x over previous
//
#include <hip/hip_runtime.h>
#include <math.h>

typedef unsigned short u16;
typedef unsigned int   u32;
typedef __attribute__((ext_vector_type(8))) short short8;
typedef __attribute__((ext_vector_type(4))) float floatx4;
typedef __attribute__((ext_vector_type(4))) unsigned short u16x4;

#define MFMA16(a,b,c) __builtin_amdgcn_mfma_f32_16x16x32_bf16((a),(b),(c),0,0,0)

constexpr int BB  = 2;
constexpr int NT  = 2240;
constexpr int CD  = 384;
constexpr int NH  = 6;
constexpr int HD  = 64;
constexpr int HID = 1536;
constexpr int M   = BB * NT;          // 4480
constexpr int CS  = 5;                // attn column chunks
constexpr int CTILES = NT / 64 / CS;  // 7 col-tiles per chunk
constexpr float SCALE = 0.125f;

__device__ inline u16 f2bf(float f) {
  u32 u = __float_as_uint(f);
  u = (u + 0x7fffu + ((u >> 16) & 1u)) >> 16;
  return (u16)u;
}
__device__ inline float bf2f(u16 b) { return __uint_as_float(((u32)b) << 16); }

__device__ inline uint4 sum5_bf(uint4 a0, uint4 a1, uint4 a2, uint4 a3, uint4 a4) {
  union U { uint4 v; u16 h[8]; };
  U u0, u1, u2, u3, u4, o;
  u0.v = a0; u1.v = a1; u2.v = a2; u3.v = a3; u4.v = a4;
  #pragma unroll
  for (int e = 0; e < 8; ++e) {
    float f = bf2f(u0.h[e]) + bf2f(u1.h[e]) + bf2f(u2.h[e]) + bf2f(u3.h[e]) + bf2f(u4.h[e]);
    o.h[e] = f2bf(f);
  }
  return o.v;
}

// ---------------- fused: LN1 (+pos add, x save) for blocks < M; weight cvt above ----------------
constexpr int NQ = 3 * CD * CD, NP = CD * CD, N1 = HID * CD, N2 = CD * HID;
constexpr int CVT_BLOCKS = (NQ + NP + N1 + N2) / 512;  // 128 thr x 4 elems

__global__ __launch_bounds__(128) void ln_cvt_kernel(
    const float* __restrict__ xin, const float* __restrict__ pos,
    const float* __restrict__ g, const float* __restrict__ bta,
    float* __restrict__ x1out, u16* __restrict__ hout,
    const float* __restrict__ s0, u16* __restrict__ d0,
    const float* __restrict__ s1, u16* __restrict__ d1,
    const float* __restrict__ s2, u16* __restrict__ d2,
    const float* __restrict__ s3, u16* __restrict__ d3) {
  int t = threadIdx.x;
  if (blockIdx.x >= M) {
    int i = ((blockIdx.x - M) * 128 + t) * 4;
    const float* s; u16* d; int base;
    if (i < NQ)                { s = s0; d = d0; base = 0; }
    else if (i < NQ + NP)      { s = s1; d = d1; base = NQ; }
    else if (i < NQ + NP + N1) { s = s2; d = d2; base = NQ + NP; }
    else                       { s = s3; d = d3; base = NQ + NP + N1; }
    int j = i - base;
    float4 v = *(const float4*)(s + j);
    ushort4 o; o.x = f2bf(v.x); o.y = f2bf(v.y); o.z = f2bf(v.z); o.w = f2bf(v.w);
    *(ushort4*)(d + j) = o;
    return;
  }
  int row = blockIdx.x;
  int n = row % NT;
  const float* xr = xin + (size_t)row * CD;
  float v[3], s1v = 0.f, s2v = 0.f;
  #pragma unroll
  for (int j = 0; j < 3; ++j) {
    int c = t + j * 128;
    float x = xr[c] + pos[(size_t)n * CD + c];
    v[j] = x; s1v += x; s2v += x * x;
  }
  #pragma unroll
  for (int off = 32; off; off >>= 1) { s1v += __shfl_down(s1v, off); s2v += __shfl_down(s2v, off); }
  __shared__ float rbuf[4];
  __shared__ float stats[2];
  int lane = t & 63, wid = t >> 6;
  if (lane == 0) { rbuf[wid] = s1v; rbuf[2 + wid] = s2v; }
  __syncthreads();
  if (t == 0) {
    float a = rbuf[0] + rbuf[1], b2 = rbuf[2] + rbuf[3];
    float mu = a / CD;
    float var = b2 / CD - mu * mu;
    stats[0] = mu; stats[1] = rsqrtf(var + 1e-5f);
  }
  __syncthreads();
  float mu = stats[0], rs = stats[1];
  #pragma unroll
  for (int j = 0; j < 3; ++j) {
    int c = t + j * 128;
    float h = (v[j] - mu) * rs * g[c] + bta[c];
    hout[(size_t)row * CD + c] = f2bf(h);
    x1out[(size_t)row * CD + c] = v[j];
  }
}

// ---------------- plain layernorm (for LN2) ----------------
__global__ __launch_bounds__(128) void ln_kernel(
    const float* __restrict__ xin,
    const float* __restrict__ g, const float* __restrict__ bta,
    u16* __restrict__ hout) {
  int row = blockIdx.x;
  int t = threadIdx.x;
  const float* xr = xin + (size_t)row * CD;
  float v[3], s1 = 0.f, s2 = 0.f;
  #pragma unroll
  for (int j = 0; j < 3; ++j) {
    int c = t + j * 128;
    float x = xr[c];
    v[j] = x; s1 += x; s2 += x * x;
  }
  #pragma unroll
  for (int off = 32; off; off >>= 1) { s1 += __shfl_down(s1, off); s2 += __shfl_down(s2, off); }
  __shared__ float rbuf[4];
  __shared__ float stats[2];
  int lane = t & 63, wid = t >> 6;
  if (lane == 0) { rbuf[wid] = s1; rbuf[2 + wid] = s2; }
  __syncthreads();
  if (t == 0) {
    float a = rbuf[0] + rbuf[1], b2 = rbuf[2] + rbuf[3];
    float mu = a / CD;
    float var = b2 / CD - mu * mu;
    stats[0] = mu; stats[1] = rsqrtf(var + 1e-5f);
  }
  __syncthreads();
  float mu = stats[0], rs = stats[1];
  #pragma unroll
  for (int j = 0; j < 3; ++j) {
    int c = t + j * 128;
    hout[(size_t)row * CD + c] = f2bf((v[j] - mu) * rs * g[c] + bta[c]);
  }
}

// ---------------- bf16 GEMM: out[M,N] = A[M,K] @ W[N,K]^T ----------------
// Double-buffered LDS: ONE barrier per K-step (was two). Grid-limited kernels
// (~1.6 blocks/CU) can't hide barrier drains via TLP, so barrier count matters.
// Safety: iter k+1's barrier drains iter k's LDS reads before iter k+2 overwrites.
// EPI: 0 = qkv scatter   2 = fc1 (bias+gelu->bf16)   3 = fp32 out = acc+bias+res
// OSUM: A = o_part (5 bf16 slices summed during staging)
template <int EPI, bool OSUM>
__global__ __launch_bounds__(256) void gemm_bt(
    const u16* __restrict__ A, const u16* __restrict__ Wt, int K,
    const float* __restrict__ bias, const float* __restrict__ res,
    float* __restrict__ outf, u16* __restrict__ outb,
    u16* __restrict__ qout, u16* __restrict__ kout, u16* __restrict__ vtout) {
  __shared__ __align__(16) u16 As[2][64][72];
  __shared__ __align__(16) u16 Bs[2][64][72];
  int m0 = blockIdx.y * 64, n0 = blockIdx.x * 64;
  int t = threadIdx.x;
  int lane = t & 63, w = t >> 6, wm = w & 1, wn = w >> 1;
  int quad = lane >> 4, c16 = lane & 15;
  int lrow = t >> 2, lseg = t & 3;
  constexpr int SL = OSUM ? 5 : 1;
  const u16* ga[SL];
  #pragma unroll
  for (int s = 0; s < SL; ++s)
    ga[s] = A + (size_t)s * M * CD + (size_t)(m0 + lrow) * K + lseg * 8;
  const u16* gb = Wt + (size_t)(n0 + lrow) * K + lseg * 8;
  floatx4 acc[2][2] = {};
  uint4 av0[SL], av1[SL], bv0, bv1;
  #pragma unroll
  for (int s = 0; s < SL; ++s) { av0[s] = *(const uint4*)(ga[s]); av1[s] = *(const uint4*)(ga[s] + 32); }
  bv0 = *(const uint4*)(gb);
  bv1 = *(const uint4*)(gb + 32);
  int cur = 0;
  for (int k0 = 0; k0 < K; k0 += 64) {
    uint4 wa0, wa1;
    if (OSUM) {
      wa0 = sum5_bf(av0[0], av0[1], av0[2], av0[3], av0[4 % SL]);
      wa1 = sum5_bf(av1[0], av1[1], av1[2], av1[3], av1[4 % SL]);
    } else { wa0 = av0[0]; wa1 = av1[0]; }
    *(uint4*)&As[cur][lrow][lseg * 8] = wa0;
    *(uint4*)&As[cur][lrow][32 + lseg * 8] = wa1;
    *(uint4*)&Bs[cur][lrow][lseg * 8] = bv0;
    *(uint4*)&Bs[cur][lrow][32 + lseg * 8] = bv1;
    __syncthreads();   // writes to buf[cur] visible; prior reads of buf[cur] (2 iters ago) drained
    if (k0 + 64 < K) {  // prefetch next K-tile; latency hides under MFMA below
      #pragma unroll
      for (int s = 0; s < SL; ++s) {
        av0[s] = *(const uint4*)(ga[s] + k0 + 64);
        av1[s] = *(const uint4*)(ga[s] + k0 + 96);
      }
      bv0 = *(const uint4*)(gb + k0 + 64);
      bv1 = *(const uint4*)(gb + k0 + 96);
    }
    #pragma unroll
    for (int ks = 0; ks < 2; ++ks) {
      short8 af[2], bf[2];
      #pragma unroll
      for (int mt = 0; mt < 2; ++mt) af[mt] = *(const short8*)&As[cur][wm * 32 + mt * 16 + c16][ks * 32 + quad * 8];
      #pragma unroll
      for (int nt = 0; nt < 2; ++nt) bf[nt] = *(const short8*)&Bs[cur][wn * 32 + nt * 16 + c16][ks * 32 + quad * 8];
      #pragma unroll
      for (int mt = 0; mt < 2; ++mt)
        #pragma unroll
        for (int nt = 0; nt < 2; ++nt)
          acc[mt][nt] = MFMA16(af[mt], bf[nt], acc[mt][nt]);
    }
    cur ^= 1;
  }
  if (EPI == 0) {
    // qkv scatter: stage tile in LDS (transposed for V), store coalesced.
    int s = n0 / 384;                 // 0=q 1=k 2=v
    int hh = (n0 % 384) / 64;
    int b_ = m0 / NT, nn0 = m0 % NT;
    __syncthreads();
    #pragma unroll
    for (int mt = 0; mt < 2; ++mt)
      #pragma unroll
      for (int nt = 0; nt < 2; ++nt)
        #pragma unroll
        for (int r = 0; r < 4; ++r) {
          int m_l = wm * 32 + mt * 16 + quad * 4 + r;
          int d_l = wn * 32 + nt * 16 + c16;
          u16 bv = f2bf(acc[mt][nt][r]);
          if (s < 2) As[0][m_l][d_l] = bv;
          else       As[0][d_l][m_l] = bv;
        }
    __syncthreads();
    int row = t >> 2, cs0 = (t & 3) * 16;
    uint4 va = *(const uint4*)&As[0][row][cs0];
    uint4 vb = *(const uint4*)&As[0][row][cs0 + 8];
    u16* dst;
    if (s == 0)      dst = qout  + ((size_t)(b_ * NH + hh) * NT + nn0 + row) * HD + cs0;
    else if (s == 1) dst = kout  + ((size_t)(b_ * NH + hh) * NT + nn0 + row) * HD + cs0;
    else             dst = vtout + ((size_t)(b_ * NH + hh) * HD + row) * NT + nn0 + cs0;
    *(uint4*)dst = va;
    *(uint4*)(dst + 8) = vb;
  } else {
    #pragma unroll
    for (int mt = 0; mt < 2; ++mt) {
      #pragma unroll
      for (int nt = 0; nt < 2; ++nt) {
        int rg0 = m0 + wm * 32 + mt * 16 + quad * 4;
        int cg = n0 + wn * 32 + nt * 16 + c16;
        #pragma unroll
        for (int r = 0; r < 4; ++r) {
          float v = acc[mt][nt][r];
          int m = rg0 + r;
          if (EPI == 2) {
            v += bias[cg];
            v = 0.5f * v * (1.0f + erff(v * 0.70710678118f));
            outb[(size_t)m * HID + cg] = f2bf(v);
          } else {
            outf[(size_t)m * CD + cg] = v + bias[cg] + res[(size_t)m * CD + cg];
          }
        }
      }
    }
  }
}

// ---------------- attention pass 1: partial (m, l) per column chunk ----------------
// swapped-operand QK^T: mfma(K, Q) -> each lane holds 16 scores of ONE q-row.
// Double-buffered K staging: ONE barrier per tile (was two).
__global__ __launch_bounds__(256) void attn_pass1(
    const u16* __restrict__ qb, const u16* __restrict__ kb, float* __restrict__ ml) {
  __shared__ __align__(16) u16 Ks[2][64][72];
  int bh = blockIdx.y, chunk = blockIdx.z;
  int q0 = blockIdx.x * 64;
  int t = threadIdx.x, w = t >> 6, lane = t & 63, quad = lane >> 4, c16 = lane & 15;
  int lrow = t >> 2, lseg = t & 3;

  const u16* qp = qb + ((size_t)bh * NT + q0 + w * 16 + c16) * HD;
  short8 qf0 = *(const short8*)(qp + quad * 8);
  short8 qf1 = *(const short8*)(qp + 32 + quad * 8);
  const u16* kbase = kb + (size_t)bh * NT * HD;

  float m_i = -1e30f, l_i = 0.f;

  const u16* kg = kbase + (size_t)(chunk * CTILES * 64 + lrow) * HD + lseg * 8;
  uint4 kv0 = *(const uint4*)kg;
  uint4 kv1 = *(const uint4*)(kg + 32);

  int cur = 0;
  for (int ct = 0; ct < CTILES; ++ct) {
    *(uint4*)&Ks[cur][lrow][lseg * 8] = kv0;
    *(uint4*)&Ks[cur][lrow][32 + lseg * 8] = kv1;
    __syncthreads();
    if (ct + 1 < CTILES) {
      const u16* kn = kbase + (size_t)((chunk * CTILES + ct + 1) * 64 + lrow) * HD + lseg * 8;
      kv0 = *(const uint4*)kn;
      kv1 = *(const uint4*)(kn + 32);
    }
    floatx4 s_acc[4] = {};
    #pragma unroll
    for (int nt = 0; nt < 4; ++nt) {
      const u16* kp = &Ks[cur][nt * 16 + c16][quad * 8];
      s_acc[nt] = MFMA16(*(const short8*)(kp), qf0, s_acc[nt]);
      s_acc[nt] = MFMA16(*(const short8*)(kp + 32), qf1, s_acc[nt]);
    }
    float rm = -1e30f;
    #pragma unroll
    for (int nt = 0; nt < 4; ++nt)
      #pragma unroll
      for (int r = 0; r < 4; ++r) rm = fmaxf(rm, s_acc[nt][r]);
    rm *= SCALE;
    rm = fmaxf(rm, __shfl_xor(rm, 16));
    rm = fmaxf(rm, __shfl_xor(rm, 32));
    float nm = fmaxf(m_i, rm);
    float ps = 0.f;
    #pragma unroll
    for (int nt = 0; nt < 4; ++nt)
      #pragma unroll
      for (int r = 0; r < 4; ++r) ps += __expf(s_acc[nt][r] * SCALE - nm);
    ps += __shfl_xor(ps, 16);
    ps += __shfl_xor(ps, 32);
    l_i = l_i * __expf(m_i - nm) + ps;
    m_i = nm;
    cur ^= 1;
  }
  if (quad == 0) {
    int row = q0 + w * 16 + c16;
    float* p = ml + ((size_t)(bh * NT + row) * CS + chunk) * 2;
    p[0] = m_i; p[1] = l_i;
  }
}

// ---------------- attention pass 2: write attn, bf16 partial O per chunk ----------------
// Swapped-operand QK^T AND PV; packed vector stores. K/V LDS staging kept
// (R8: removal costs +86us). NOT double-buffered: LDS would go 28->47 KB and
// cut occupancy 5->3 blocks/CU at 2100-block demand.
__global__ __launch_bounds__(256) void attn_pass2(
    const u16* __restrict__ qb, const u16* __restrict__ kb, const u16* __restrict__ vtb,
    const float* __restrict__ ml, float* __restrict__ attn_out, u16* __restrict__ o_part) {
  __shared__ __align__(16) u16 Ks[64][72];
  __shared__ __align__(16) u16 Vs[64][72];
  __shared__ __align__(16) u16 Plds[4][16][72];
  __shared__ float mfin[64], rlfin[64];
  int bh = blockIdx.y, chunk = blockIdx.z;
  int b = bh / NH, hh = bh % NH;
  int q0 = blockIdx.x * 64;
  int t = threadIdx.x, w = t >> 6, lane = t & 63, quad = lane >> 4, c16 = lane & 15;
  int lrow = t >> 2, lseg = t & 3;

  const u16* kbase = kb + (size_t)bh * NT * HD;
  const u16* vbase = vtb + (size_t)bh * HD * NT;

  // issue tile-0 loads first so latency hides under the ml-combine phase
  int col00 = chunk * CTILES * 64;
  const u16* kg = kbase + (size_t)(col00 + lrow) * HD + lseg * 8;
  const u16* vg = vbase + (size_t)lrow * NT + col00 + lseg * 8;
  uint4 kv0 = *(const uint4*)kg;
  uint4 kv1 = *(const uint4*)(kg + 32);
  uint4 vv0 = *(const uint4*)vg;
  uint4 vv1 = *(const uint4*)(vg + 32);

  if (t < 64) {
    const float* p = ml + (size_t)(bh * NT + q0 + t) * CS * 2;
    float mm = -1e30f;
    #pragma unroll
    for (int c = 0; c < CS; ++c) mm = fmaxf(mm, p[c * 2]);
    float ll = 0.f;
    #pragma unroll
    for (int c = 0; c < CS; ++c) ll += p[c * 2 + 1] * __expf(p[c * 2] - mm);
    mfin[t] = mm; rlfin[t] = 1.0f / ll;
  }
  __syncthreads();
  // swapped layout: each lane owns q-row w*16+c16 -> scalar (m, 1/l)
  float m_i = mfin[w * 16 + c16];
  float rl  = rlfin[w * 16 + c16];

  const u16* qp = qb + ((size_t)bh * NT + q0 + w * 16 + c16) * HD;
  short8 qf0 = *(const short8*)(qp + quad * 8);
  short8 qf1 = *(const short8*)(qp + 32 + quad * 8);

  int qrow = q0 + w * 16 + c16;
  floatx4 o_acc[4] = {};
  float* attn_bh = attn_out + (size_t)bh * NT * NT;
  for (int ct = 0; ct < CTILES; ++ct) {
    int col0 = (chunk * CTILES + ct) * 64;
    __syncthreads();
    *(uint4*)&Ks[lrow][lseg * 8] = kv0;
    *(uint4*)&Ks[lrow][32 + lseg * 8] = kv1;
    *(uint4*)&Vs[lrow][lseg * 8] = vv0;
    *(uint4*)&Vs[lrow][32 + lseg * 8] = vv1;
    __syncthreads();
    if (ct + 1 < CTILES) {
      int coln = col0 + 64;
      const u16* kn = kbase + (size_t)(coln + lrow) * HD + lseg * 8;
      const u16* vn = vbase + (size_t)lrow * NT + coln + lseg * 8;
      kv0 = *(const uint4*)kn;
      kv1 = *(const uint4*)(kn + 32);
      vv0 = *(const uint4*)vn;
      vv1 = *(const uint4*)(vn + 32);
    }
    // swapped QK^T: s_acc[nt][r] = S[qrow = w*16+c16][kcol = nt*16 + quad*4 + r]
    floatx4 s_acc[4] = {};
    #pragma unroll
    for (int nt = 0; nt < 4; ++nt) {
      const u16* kp = &Ks[nt * 16 + c16][quad * 8];
      s_acc[nt] = MFMA16(*(const short8*)(kp), qf0, s_acc[nt]);
      s_acc[nt] = MFMA16(*(const short8*)(kp + 32), qf1, s_acc[nt]);
    }
    #pragma unroll
    for (int nt = 0; nt < 4; ++nt) {
      floatx4 pv;
      u16x4 ph;
      #pragma unroll
      for (int r = 0; r < 4; ++r) {
        float p = __expf(s_acc[nt][r] * SCALE - m_i) * rl;
        pv[r] = p;
        ph[r] = f2bf(p);
      }
      __builtin_nontemporal_store(
          pv, (floatx4*)&attn_bh[(size_t)qrow * NT + col0 + nt * 16 + quad * 4]);
      *(u16x4*)&Plds[w][c16][nt * 16 + quad * 4] = ph;
    }
    // PV (swapped: A=V^T, B=P): o_acc[dt][r] = O[qrow][d = dt*16 + quad*4 + r]
    #pragma unroll
    for (int ks = 0; ks < 2; ++ks) {
      short8 pa = *(const short8*)&Plds[w][c16][ks * 32 + quad * 8];
      #pragma unroll
      for (int dt = 0; dt < 4; ++dt) {
        short8 vb = *(const short8*)&Vs[dt * 16 + c16][ks * 32 + quad * 8];
        o_acc[dt] = MFMA16(vb, pa, o_acc[dt]);
      }
    }
  }
  int m = b * NT + qrow;
  #pragma unroll
  for (int dt = 0; dt < 4; ++dt) {
    u16x4 oh;
    #pragma unroll
    for (int r = 0; r < 4; ++r) oh[r] = f2bf(o_acc[dt][r]);
    *(u16x4*)&o_part[((size_t)chunk * M + m) * CD + hh * 64 + dt * 16 + quad * 4] = oh;
  }
}

// ---------------- launch ----------------
extern "C" void kernel_launch(void* const* d_in, const int* in_sizes, int n_in,
                              void* d_out, int out_size, void* d_ws, size_t ws_size,
                              hipStream_t stream) {
  const float* x      = (const float*)d_in[0];
  const float* pos    = (const float*)d_in[1];
  const float* ln1_g  = (const float*)d_in[2];
  const float* ln1_b  = (const float*)d_in[3];
  const float* w_qkv  = (const float*)d_in[4];
  const float* w_proj = (const float*)d_in[5];
  const float* b_proj = (const float*)d_in[6];
  const float* ln2_g  = (const float*)d_in[7];
  const float* ln2_b  = (const float*)d_in[8];
  const float* w_fc1  = (const float*)d_in[9];
  const float* b_fc1  = (const float*)d_in[10];
  const float* w_fc2  = (const float*)d_in[11];
  const float* b_fc2  = (const float*)d_in[12];

  float* out      = (float*)d_out;
  float* attn_out = out + (size_t)M * CD;

  char* ws = (char*)d_ws;
  size_t o = 0;
  auto carve = [&](size_t bytes) { char* p = ws + o; o += bytes; return p; };
  float* x1    = (float*)carve((size_t)M * CD * 4);
  u16* h1      = (u16*)carve((size_t)M * CD * 2);
  u16* wqkv_b  = (u16*)carve((size_t)3 * CD * CD * 2);
  u16* wproj_b = (u16*)carve((size_t)CD * CD * 2);
  u16* wfc1_b  = (u16*)carve((size_t)HID * CD * 2);
  u16* wfc2_b  = (u16*)carve((size_t)CD * HID * 2);
  u16* q_bf    = (u16*)carve((size_t)BB * NH * NT * HD * 2);
  u16* k_bf    = (u16*)carve((size_t)BB * NH * NT * HD * 2);
  u16* vt_bf   = (u16*)carve((size_t)BB * NH * NT * HD * 2);
  float* x2    = (float*)carve((size_t)M * CD * 4);
  u16* h2      = (u16*)carve((size_t)M * CD * 2);
  u16* g_bf    = (u16*)carve((size_t)M * HID * 2);
  float* ml    = (float*)carve((size_t)NH * BB * NT * CS * 2 * 4);
  u16* o_part  = (u16*)carve((size_t)CS * M * CD * 2);
  (void)ws_size; (void)in_sizes; (void)n_in; (void)out_size;

  // LN1 (+pos, x1 save) and all weight converts in ONE launch
  ln_cvt_kernel<<<M + CVT_BLOCKS, 128, 0, stream>>>(
      x, pos, ln1_g, ln1_b, x1, h1,
      w_qkv, wqkv_b, w_proj, wproj_b, w_fc1, wfc1_b, w_fc2, wfc2_b);

  // qkv = h1 @ w_qkv^T, scatter to q/k/vT (coalesced via LDS transpose)
  gemm_bt<0, false><<<dim3((3 * CD) / 64, M / 64), 256, 0, stream>>>(
      h1, wqkv_b, CD, nullptr, nullptr, nullptr, nullptr, q_bf, k_bf, vt_bf);

  // attention (column-chunked two-pass, LDS-staged K/V tiles, prefetch pipelined)
  attn_pass1<<<dim3(NT / 64, BB * NH, CS), 256, 0, stream>>>(q_bf, k_bf, ml);
  attn_pass2<<<dim3(NT / 64, BB * NH, CS), 256, 0, stream>>>(q_bf, k_bf, vt_bf, ml, attn_out, o_part);

  // x2 = x1 + b_proj + (sum o_part) @ w_proj^T   (osum fused into A-staging)
  gemm_bt<3, true><<<dim3(CD / 64, M / 64), 256, 0, stream>>>(
      o_part, wproj_b, CD, b_proj, x1, x2, nullptr, nullptr, nullptr, nullptr);
  ln_kernel<<<M, 128, 0, stream>>>(x2, ln2_g, ln2_b, h2);

  // g = gelu(h2 @ w_fc1^T + b_fc1)
  gemm_bt<2, false><<<dim3(HID / 64, M / 64), 256, 0, stream>>>(
      h2, wfc1_b, CD, b_fc1, nullptr, nullptr, g_bf, nullptr, nullptr, nullptr);

  // out = x2 + b_fc2 + g @ w_fc2^T (direct K=1536, fused residual)
  gemm_bt<3, false><<<dim3(CD / 64, M / 64), 256, 0, stream>>>(
      g_bf, wfc2_b, HID, b_fc2, x2, out, nullptr, nullptr, nullptr, nullptr);
}

// Round 12
// 398.529 us; speedup vs baseline: 1.2450x; 1.0002x over previous
//
#include <hip/hip_runtime.h>
#include <math.h>

typedef unsigned short u16;
typedef unsigned int   u32;
typedef __attribute__((ext_vector_type(8))) short short8;
typedef __attribute__((ext_vector_type(4))) float floatx4;
typedef __attribute__((ext_vector_type(4))) unsigned short u16x4;

#define MFMA16(a,b,c) __builtin_amdgcn_mfma_f32_16x16x32_bf16((a),(b),(c),0,0,0)

constexpr int BB  = 2;
constexpr int NT  = 2240;
constexpr int CD  = 384;
constexpr int NH  = 6;
constexpr int HD  = 64;
constexpr int HID = 1536;
constexpr int M   = BB * NT;          // 4480
constexpr int CS  = 5;                // attn column chunks
constexpr int CTILES = NT / 64 / CS;  // 7 col-tiles per chunk
constexpr float SCALE = 0.125f;

__device__ inline u16 f2bf(float f) {
  u32 u = __float_as_uint(f);
  u = (u + 0x7fffu + ((u >> 16) & 1u)) >> 16;
  return (u16)u;
}
__device__ inline float bf2f(u16 b) { return __uint_as_float(((u32)b) << 16); }

__device__ inline uint4 sum5_bf(uint4 a0, uint4 a1, uint4 a2, uint4 a3, uint4 a4) {
  union U { uint4 v; u16 h[8]; };
  U u0, u1, u2, u3, u4, o;
  u0.v = a0; u1.v = a1; u2.v = a2; u3.v = a3; u4.v = a4;
  #pragma unroll
  for (int e = 0; e < 8; ++e) {
    float f = bf2f(u0.h[e]) + bf2f(u1.h[e]) + bf2f(u2.h[e]) + bf2f(u3.h[e]) + bf2f(u4.h[e]);
    o.h[e] = f2bf(f);
  }
  return o.v;
}

// ---------------- fused: LN1 (+pos add, x save) for blocks < M; weight cvt above ----------------
constexpr int NQ = 3 * CD * CD, NP = CD * CD, N1 = HID * CD, N2 = CD * HID;
constexpr int CVT_BLOCKS = (NQ + NP + N1 + N2) / 512;  // 128 thr x 4 elems

__global__ __launch_bounds__(128) void ln_cvt_kernel(
    const float* __restrict__ xin, const float* __restrict__ pos,
    const float* __restrict__ g, const float* __restrict__ bta,
    float* __restrict__ x1out, u16* __restrict__ hout,
    const float* __restrict__ s0, u16* __restrict__ d0,
    const float* __restrict__ s1, u16* __restrict__ d1,
    const float* __restrict__ s2, u16* __restrict__ d2,
    const float* __restrict__ s3, u16* __restrict__ d3) {
  int t = threadIdx.x;
  if (blockIdx.x >= M) {
    int i = ((blockIdx.x - M) * 128 + t) * 4;
    const float* s; u16* d; int base;
    if (i < NQ)                { s = s0; d = d0; base = 0; }
    else if (i < NQ + NP)      { s = s1; d = d1; base = NQ; }
    else if (i < NQ + NP + N1) { s = s2; d = d2; base = NQ + NP; }
    else                       { s = s3; d = d3; base = NQ + NP + N1; }
    int j = i - base;
    float4 v = *(const float4*)(s + j);
    ushort4 o; o.x = f2bf(v.x); o.y = f2bf(v.y); o.z = f2bf(v.z); o.w = f2bf(v.w);
    *(ushort4*)(d + j) = o;
    return;
  }
  int row = blockIdx.x;
  int n = row % NT;
  const float* xr = xin + (size_t)row * CD;
  float v[3], s1v = 0.f, s2v = 0.f;
  #pragma unroll
  for (int j = 0; j < 3; ++j) {
    int c = t + j * 128;
    float x = xr[c] + pos[(size_t)n * CD + c];
    v[j] = x; s1v += x; s2v += x * x;
  }
  #pragma unroll
  for (int off = 32; off; off >>= 1) { s1v += __shfl_down(s1v, off); s2v += __shfl_down(s2v, off); }
  __shared__ float rbuf[4];
  __shared__ float stats[2];
  int lane = t & 63, wid = t >> 6;
  if (lane == 0) { rbuf[wid] = s1v; rbuf[2 + wid] = s2v; }
  __syncthreads();
  if (t == 0) {
    float a = rbuf[0] + rbuf[1], b2 = rbuf[2] + rbuf[3];
    float mu = a / CD;
    float var = b2 / CD - mu * mu;
    stats[0] = mu; stats[1] = rsqrtf(var + 1e-5f);
  }
  __syncthreads();
  float mu = stats[0], rs = stats[1];
  #pragma unroll
  for (int j = 0; j < 3; ++j) {
    int c = t + j * 128;
    float h = (v[j] - mu) * rs * g[c] + bta[c];
    hout[(size_t)row * CD + c] = f2bf(h);
    x1out[(size_t)row * CD + c] = v[j];
  }
}

// ---------------- plain layernorm (for LN2) ----------------
__global__ __launch_bounds__(128) void ln_kernel(
    const float* __restrict__ xin,
    const float* __restrict__ g, const float* __restrict__ bta,
    u16* __restrict__ hout) {
  int row = blockIdx.x;
  int t = threadIdx.x;
  const float* xr = xin + (size_t)row * CD;
  float v[3], s1 = 0.f, s2 = 0.f;
  #pragma unroll
  for (int j = 0; j < 3; ++j) {
    int c = t + j * 128;
    float x = xr[c];
    v[j] = x; s1 += x; s2 += x * x;
  }
  #pragma unroll
  for (int off = 32; off; off >>= 1) { s1 += __shfl_down(s1, off); s2 += __shfl_down(s2, off); }
  __shared__ float rbuf[4];
  __shared__ float stats[2];
  int lane = t & 63, wid = t >> 6;
  if (lane == 0) { rbuf[wid] = s1; rbuf[2 + wid] = s2; }
  __syncthreads();
  if (t == 0) {
    float a = rbuf[0] + rbuf[1], b2 = rbuf[2] + rbuf[3];
    float mu = a / CD;
    float var = b2 / CD - mu * mu;
    stats[0] = mu; stats[1] = rsqrtf(var + 1e-5f);
  }
  __syncthreads();
  float mu = stats[0], rs = stats[1];
  #pragma unroll
  for (int j = 0; j < 3; ++j) {
    int c = t + j * 128;
    hout[(size_t)row * CD + c] = f2bf((v[j] - mu) * rs * g[c] + bta[c]);
  }
}

// ---------------- bf16 GEMM: out[M,N] = A[M,K] @ W[N,K]^T ----------------
// Double-buffered LDS, ONE barrier per K-step (R11).
// Non-OSUM: 2-DEEP register prefetch (K-loop unrolled 2x, sets A/B): the load
// for tile k+2 is issued a FULL iteration before its ds_write consumes it, so
// L2/HBM latency (~200-900cy) hides under the intervening MFMA+barrier phases.
// (1-deep left only a ~50-80cy gap -> per-iter vmcnt stall on grid-limited
// kernels with too few waves/CU to hide it.) Requires K % 128 == 0 (384, 1536 ok).
// OSUM (proj, K=384): keeps 1-deep (2-deep x5 slices would cost +40 VGPR).
// EPI: 0 = qkv scatter   2 = fc1 (bias+gelu->bf16)   3 = fp32 out = acc+bias+res
template <int EPI, bool OSUM>
__global__ __launch_bounds__(256) void gemm_bt(
    const u16* __restrict__ A, const u16* __restrict__ Wt, int K,
    const float* __restrict__ bias, const float* __restrict__ res,
    float* __restrict__ outf, u16* __restrict__ outb,
    u16* __restrict__ qout, u16* __restrict__ kout, u16* __restrict__ vtout) {
  __shared__ __align__(16) u16 As[2][64][72];
  __shared__ __align__(16) u16 Bs[2][64][72];
  int m0 = blockIdx.y * 64, n0 = blockIdx.x * 64;
  int t = threadIdx.x;
  int lane = t & 63, w = t >> 6, wm = w & 1, wn = w >> 1;
  int quad = lane >> 4, c16 = lane & 15;
  int lrow = t >> 2, lseg = t & 3;
  floatx4 acc[2][2] = {};

  auto mfma_phase = [&](int c) {
    #pragma unroll
    for (int ks = 0; ks < 2; ++ks) {
      short8 af[2], bf[2];
      #pragma unroll
      for (int mt = 0; mt < 2; ++mt) af[mt] = *(const short8*)&As[c][wm * 32 + mt * 16 + c16][ks * 32 + quad * 8];
      #pragma unroll
      for (int nt = 0; nt < 2; ++nt) bf[nt] = *(const short8*)&Bs[c][wn * 32 + nt * 16 + c16][ks * 32 + quad * 8];
      #pragma unroll
      for (int mt = 0; mt < 2; ++mt)
        #pragma unroll
        for (int nt = 0; nt < 2; ++nt)
          acc[mt][nt] = MFMA16(af[mt], bf[nt], acc[mt][nt]);
    }
  };

  if constexpr (!OSUM) {
    const u16* ga = A + (size_t)(m0 + lrow) * K + lseg * 8;
    const u16* gb = Wt + (size_t)(n0 + lrow) * K + lseg * 8;
    // set A = tile k0, set B = tile k0+64
    uint4 aA0 = *(const uint4*)(ga);
    uint4 aA1 = *(const uint4*)(ga + 32);
    uint4 bA0 = *(const uint4*)(gb);
    uint4 bA1 = *(const uint4*)(gb + 32);
    uint4 aB0 = *(const uint4*)(ga + 64);
    uint4 aB1 = *(const uint4*)(ga + 96);
    uint4 bB0 = *(const uint4*)(gb + 64);
    uint4 bB1 = *(const uint4*)(gb + 96);
    int cur = 0;
    for (int k0 = 0; k0 < K; k0 += 128) {
      // half-iter A (tile k0)
      *(uint4*)&As[cur][lrow][lseg * 8] = aA0;
      *(uint4*)&As[cur][lrow][32 + lseg * 8] = aA1;
      *(uint4*)&Bs[cur][lrow][lseg * 8] = bA0;
      *(uint4*)&Bs[cur][lrow][32 + lseg * 8] = bA1;
      __syncthreads();
      if (k0 + 128 < K) {  // prefetch tile k0+128 (consumed next full iter)
        aA0 = *(const uint4*)(ga + k0 + 128);
        aA1 = *(const uint4*)(ga + k0 + 160);
        bA0 = *(const uint4*)(gb + k0 + 128);
        bA1 = *(const uint4*)(gb + k0 + 160);
      }
      mfma_phase(cur);
      cur ^= 1;
      // half-iter B (tile k0+64)
      *(uint4*)&As[cur][lrow][lseg * 8] = aB0;
      *(uint4*)&As[cur][lrow][32 + lseg * 8] = aB1;
      *(uint4*)&Bs[cur][lrow][lseg * 8] = bB0;
      *(uint4*)&Bs[cur][lrow][32 + lseg * 8] = bB1;
      __syncthreads();
      if (k0 + 192 < K) {  // prefetch tile k0+192
        aB0 = *(const uint4*)(ga + k0 + 192);
        aB1 = *(const uint4*)(ga + k0 + 224);
        bB0 = *(const uint4*)(gb + k0 + 192);
        bB1 = *(const uint4*)(gb + k0 + 224);
      }
      mfma_phase(cur);
      cur ^= 1;
    }
  } else {
    constexpr int SL = 5;
    const u16* ga[SL];
    #pragma unroll
    for (int s = 0; s < SL; ++s)
      ga[s] = A + (size_t)s * M * CD + (size_t)(m0 + lrow) * K + lseg * 8;
    const u16* gb = Wt + (size_t)(n0 + lrow) * K + lseg * 8;
    uint4 av0[SL], av1[SL], bv0, bv1;
    #pragma unroll
    for (int s = 0; s < SL; ++s) { av0[s] = *(const uint4*)(ga[s]); av1[s] = *(const uint4*)(ga[s] + 32); }
    bv0 = *(const uint4*)(gb);
    bv1 = *(const uint4*)(gb + 32);
    int cur = 0;
    for (int k0 = 0; k0 < K; k0 += 64) {
      uint4 wa0 = sum5_bf(av0[0], av0[1], av0[2], av0[3], av0[4]);
      uint4 wa1 = sum5_bf(av1[0], av1[1], av1[2], av1[3], av1[4]);
      *(uint4*)&As[cur][lrow][lseg * 8] = wa0;
      *(uint4*)&As[cur][lrow][32 + lseg * 8] = wa1;
      *(uint4*)&Bs[cur][lrow][lseg * 8] = bv0;
      *(uint4*)&Bs[cur][lrow][32 + lseg * 8] = bv1;
      __syncthreads();
      if (k0 + 64 < K) {
        #pragma unroll
        for (int s = 0; s < SL; ++s) {
          av0[s] = *(const uint4*)(ga[s] + k0 + 64);
          av1[s] = *(const uint4*)(ga[s] + k0 + 96);
        }
        bv0 = *(const uint4*)(gb + k0 + 64);
        bv1 = *(const uint4*)(gb + k0 + 96);
      }
      mfma_phase(cur);
      cur ^= 1;
    }
  }

  if constexpr (EPI == 0) {
    // qkv scatter: stage tile in LDS (transposed for V), store coalesced.
    int s = n0 / 384;                 // 0=q 1=k 2=v
    int hh = (n0 % 384) / 64;
    int b_ = m0 / NT, nn0 = m0 % NT;
    __syncthreads();
    #pragma unroll
    for (int mt = 0; mt < 2; ++mt)
      #pragma unroll
      for (int nt = 0; nt < 2; ++nt)
        #pragma unroll
        for (int r = 0; r < 4; ++r) {
          int m_l = wm * 32 + mt * 16 + quad * 4 + r;
          int d_l = wn * 32 + nt * 16 + c16;
          u16 bv = f2bf(acc[mt][nt][r]);
          if (s < 2) As[0][m_l][d_l] = bv;
          else       As[0][d_l][m_l] = bv;
        }
    __syncthreads();
    int row = t >> 2, cs0 = (t & 3) * 16;
    uint4 va = *(const uint4*)&As[0][row][cs0];
    uint4 vb = *(const uint4*)&As[0][row][cs0 + 8];
    u16* dst;
    if (s == 0)      dst = qout  + ((size_t)(b_ * NH + hh) * NT + nn0 + row) * HD + cs0;
    else if (s == 1) dst = kout  + ((size_t)(b_ * NH + hh) * NT + nn0 + row) * HD + cs0;
    else             dst = vtout + ((size_t)(b_ * NH + hh) * HD + row) * NT + nn0 + cs0;
    *(uint4*)dst = va;
    *(uint4*)(dst + 8) = vb;
  } else {
    #pragma unroll
    for (int mt = 0; mt < 2; ++mt) {
      #pragma unroll
      for (int nt = 0; nt < 2; ++nt) {
        int rg0 = m0 + wm * 32 + mt * 16 + quad * 4;
        int cg = n0 + wn * 32 + nt * 16 + c16;
        #pragma unroll
        for (int r = 0; r < 4; ++r) {
          float v = acc[mt][nt][r];
          int m = rg0 + r;
          if constexpr (EPI == 2) {
            v += bias[cg];
            v = 0.5f * v * (1.0f + erff(v * 0.70710678118f));
            outb[(size_t)m * HID + cg] = f2bf(v);
          } else {
            outf[(size_t)m * CD + cg] = v + bias[cg] + res[(size_t)m * CD + cg];
          }
        }
      }
    }
  }
}

// ---------------- attention pass 1: partial (m, l) per column chunk ----------------
// swapped-operand QK^T: mfma(K, Q) -> each lane holds 16 scores of ONE q-row.
// Double-buffered K staging: ONE barrier per tile.
__global__ __launch_bounds__(256) void attn_pass1(
    const u16* __restrict__ qb, const u16* __restrict__ kb, float* __restrict__ ml) {
  __shared__ __align__(16) u16 Ks[2][64][72];
  int bh = blockIdx.y, chunk = blockIdx.z;
  int q0 = blockIdx.x * 64;
  int t = threadIdx.x, w = t >> 6, lane = t & 63, quad = lane >> 4, c16 = lane & 15;
  int lrow = t >> 2, lseg = t & 3;

  const u16* qp = qb + ((size_t)bh * NT + q0 + w * 16 + c16) * HD;
  short8 qf0 = *(const short8*)(qp + quad * 8);
  short8 qf1 = *(const short8*)(qp + 32 + quad * 8);
  const u16* kbase = kb + (size_t)bh * NT * HD;

  float m_i = -1e30f, l_i = 0.f;

  const u16* kg = kbase + (size_t)(chunk * CTILES * 64 + lrow) * HD + lseg * 8;
  uint4 kv0 = *(const uint4*)kg;
  uint4 kv1 = *(const uint4*)(kg + 32);

  int cur = 0;
  for (int ct = 0; ct < CTILES; ++ct) {
    *(uint4*)&Ks[cur][lrow][lseg * 8] = kv0;
    *(uint4*)&Ks[cur][lrow][32 + lseg * 8] = kv1;
    __syncthreads();
    if (ct + 1 < CTILES) {
      const u16* kn = kbase + (size_t)((chunk * CTILES + ct + 1) * 64 + lrow) * HD + lseg * 8;
      kv0 = *(const uint4*)kn;
      kv1 = *(const uint4*)(kn + 32);
    }
    floatx4 s_acc[4] = {};
    #pragma unroll
    for (int nt = 0; nt < 4; ++nt) {
      const u16* kp = &Ks[cur][nt * 16 + c16][quad * 8];
      s_acc[nt] = MFMA16(*(const short8*)(kp), qf0, s_acc[nt]);
      s_acc[nt] = MFMA16(*(const short8*)(kp + 32), qf1, s_acc[nt]);
    }
    float rm = -1e30f;
    #pragma unroll
    for (int nt = 0; nt < 4; ++nt)
      #pragma unroll
      for (int r = 0; r < 4; ++r) rm = fmaxf(rm, s_acc[nt][r]);
    rm *= SCALE;
    rm = fmaxf(rm, __shfl_xor(rm, 16));
    rm = fmaxf(rm, __shfl_xor(rm, 32));
    float nm = fmaxf(m_i, rm);
    float ps = 0.f;
    #pragma unroll
    for (int nt = 0; nt < 4; ++nt)
      #pragma unroll
      for (int r = 0; r < 4; ++r) ps += __expf(s_acc[nt][r] * SCALE - nm);
    ps += __shfl_xor(ps, 16);
    ps += __shfl_xor(ps, 32);
    l_i = l_i * __expf(m_i - nm) + ps;
    m_i = nm;
    cur ^= 1;
  }
  if (quad == 0) {
    int row = q0 + w * 16 + c16;
    float* p = ml + ((size_t)(bh * NT + row) * CS + chunk) * 2;
    p[0] = m_i; p[1] = l_i;
  }
}

// ---------------- attention pass 2: write attn, bf16 partial O per chunk ----------------
// Swapped-operand QK^T AND PV; packed vector stores. K/V LDS staging kept
// (R8: removal costs +86us). NOT double-buffered: LDS would go 28->47 KB and
// cut occupancy 5->3 blocks/CU at 2100-block demand.
__global__ __launch_bounds__(256) void attn_pass2(
    const u16* __restrict__ qb, const u16* __restrict__ kb, const u16* __restrict__ vtb,
    const float* __restrict__ ml, float* __restrict__ attn_out, u16* __restrict__ o_part) {
  __shared__ __align__(16) u16 Ks[64][72];
  __shared__ __align__(16) u16 Vs[64][72];
  __shared__ __align__(16) u16 Plds[4][16][72];
  __shared__ float mfin[64], rlfin[64];
  int bh = blockIdx.y, chunk = blockIdx.z;
  int b = bh / NH, hh = bh % NH;
  int q0 = blockIdx.x * 64;
  int t = threadIdx.x, w = t >> 6, lane = t & 63, quad = lane >> 4, c16 = lane & 15;
  int lrow = t >> 2, lseg = t & 3;

  const u16* kbase = kb + (size_t)bh * NT * HD;
  const u16* vbase = vtb + (size_t)bh * HD * NT;

  // issue tile-0 loads first so latency hides under the ml-combine phase
  int col00 = chunk * CTILES * 64;
  const u16* kg = kbase + (size_t)(col00 + lrow) * HD + lseg * 8;
  const u16* vg = vbase + (size_t)lrow * NT + col00 + lseg * 8;
  uint4 kv0 = *(const uint4*)kg;
  uint4 kv1 = *(const uint4*)(kg + 32);
  uint4 vv0 = *(const uint4*)vg;
  uint4 vv1 = *(const uint4*)(vg + 32);

  if (t < 64) {
    const float* p = ml + (size_t)(bh * NT + q0 + t) * CS * 2;
    float mm = -1e30f;
    #pragma unroll
    for (int c = 0; c < CS; ++c) mm = fmaxf(mm, p[c * 2]);
    float ll = 0.f;
    #pragma unroll
    for (int c = 0; c < CS; ++c) ll += p[c * 2 + 1] * __expf(p[c * 2] - mm);
    mfin[t] = mm; rlfin[t] = 1.0f / ll;
  }
  __syncthreads();
  // swapped layout: each lane owns q-row w*16+c16 -> scalar (m, 1/l)
  float m_i = mfin[w * 16 + c16];
  float rl  = rlfin[w * 16 + c16];

  const u16* qp = qb + ((size_t)bh * NT + q0 + w * 16 + c16) * HD;
  short8 qf0 = *(const short8*)(qp + quad * 8);
  short8 qf1 = *(const short8*)(qp + 32 + quad * 8);

  int qrow = q0 + w * 16 + c16;
  floatx4 o_acc[4] = {};
  float* attn_bh = attn_out + (size_t)bh * NT * NT;
  for (int ct = 0; ct < CTILES; ++ct) {
    int col0 = (chunk * CTILES + ct) * 64;
    __syncthreads();
    *(uint4*)&Ks[lrow][lseg * 8] = kv0;
    *(uint4*)&Ks[lrow][32 + lseg * 8] = kv1;
    *(uint4*)&Vs[lrow][lseg * 8] = vv0;
    *(uint4*)&Vs[lrow][32 + lseg * 8] = vv1;
    __syncthreads();
    if (ct + 1 < CTILES) {
      int coln = col0 + 64;
      const u16* kn = kbase + (size_t)(coln + lrow) * HD + lseg * 8;
      const u16* vn = vbase + (size_t)lrow * NT + coln + lseg * 8;
      kv0 = *(const uint4*)kn;
      kv1 = *(const uint4*)(kn + 32);
      vv0 = *(const uint4*)vn;
      vv1 = *(const uint4*)(vn + 32);
    }
    // swapped QK^T: s_acc[nt][r] = S[qrow = w*16+c16][kcol = nt*16 + quad*4 + r]
    floatx4 s_acc[4] = {};
    #pragma unroll
    for (int nt = 0; nt < 4; ++nt) {
      const u16* kp = &Ks[nt * 16 + c16][quad * 8];
      s_acc[nt] = MFMA16(*(const short8*)(kp), qf0, s_acc[nt]);
      s_acc[nt] = MFMA16(*(const short8*)(kp + 32), qf1, s_acc[nt]);
    }
    #pragma unroll
    for (int nt = 0; nt < 4; ++nt) {
      floatx4 pv;
      u16x4 ph;
      #pragma unroll
      for (int r = 0; r < 4; ++r) {
        float p = __expf(s_acc[nt][r] * SCALE - m_i) * rl;
        pv[r] = p;
        ph[r] = f2bf(p);
      }
      __builtin_nontemporal_store(
          pv, (floatx4*)&attn_bh[(size_t)qrow * NT + col0 + nt * 16 + quad * 4]);
      *(u16x4*)&Plds[w][c16][nt * 16 + quad * 4] = ph;
    }
    // PV (swapped: A=V^T, B=P): o_acc[dt][r] = O[qrow][d = dt*16 + quad*4 + r]
    #pragma unroll
    for (int ks = 0; ks < 2; ++ks) {
      short8 pa = *(const short8*)&Plds[w][c16][ks * 32 + quad * 8];
      #pragma unroll
      for (int dt = 0; dt < 4; ++dt) {
        short8 vb = *(const short8*)&Vs[dt * 16 + c16][ks * 32 + quad * 8];
        o_acc[dt] = MFMA16(vb, pa, o_acc[dt]);
      }
    }
  }
  int m = b * NT + qrow;
  #pragma unroll
  for (int dt = 0; dt < 4; ++dt) {
    u16x4 oh;
    #pragma unroll
    for (int r = 0; r < 4; ++r) oh[r] = f2bf(o_acc[dt][r]);
    *(u16x4*)&o_part[((size_t)chunk * M + m) * CD + hh * 64 + dt * 16 + quad * 4] = oh;
  }
}

// ---------------- launch ----------------
extern "C" void kernel_launch(void* const* d_in, const int* in_sizes, int n_in,
                              void* d_out, int out_size, void* d_ws, size_t ws_size,
                              hipStream_t stream) {
  const float* x      = (const float*)d_in[0];
  const float* pos    = (const float*)d_in[1];
  const float* ln1_g  = (const float*)d_in[2];
  const float* ln1_b  = (const float*)d_in[3];
  const float* w_qkv  = (const float*)d_in[4];
  const float* w_proj = (const float*)d_in[5];
  const float* b_proj = (const float*)d_in[6];
  const float* ln2_g  = (const float*)d_in[7];
  const float* ln2_b  = (const float*)d_in[8];
  const float* w_fc1  = (const float*)d_in[9];
  const float* b_fc1  = (const float*)d_in[10];
  const float* w_fc2  = (const float*)d_in[11];
  const float* b_fc2  = (const float*)d_in[12];

  float* out      = (float*)d_out;
  float* attn_out = out + (size_t)M * CD;

  char* ws = (char*)d_ws;
  size_t o = 0;
  auto carve = [&](size_t bytes) { char* p = ws + o; o += bytes; return p; };
  float* x1    = (float*)carve((size_t)M * CD * 4);
  u16* h1      = (u16*)carve((size_t)M * CD * 2);
  u16* wqkv_b  = (u16*)carve((size_t)3 * CD * CD * 2);
  u16* wproj_b = (u16*)carve((size_t)CD * CD * 2);
  u16* wfc1_b  = (u16*)carve((size_t)HID * CD * 2);
  u16* wfc2_b  = (u16*)carve((size_t)CD * HID * 2);
  u16* q_bf    = (u16*)carve((size_t)BB * NH * NT * HD * 2);
  u16* k_bf    = (u16*)carve((size_t)BB * NH * NT * HD * 2);
  u16* vt_bf   = (u16*)carve((size_t)BB * NH * NT * HD * 2);
  float* x2    = (float*)carve((size_t)M * CD * 4);
  u16* h2      = (u16*)carve((size_t)M * CD * 2);
  u16* g_bf    = (u16*)carve((size_t)M * HID * 2);
  float* ml    = (float*)carve((size_t)NH * BB * NT * CS * 2 * 4);
  u16* o_part  = (u16*)carve((size_t)CS * M * CD * 2);
  (void)ws_size; (void)in_sizes; (void)n_in; (void)out_size;

  // LN1 (+pos, x1 save) and all weight converts in ONE launch
  ln_cvt_kernel<<<M + CVT_BLOCKS, 128, 0, stream>>>(
      x, pos, ln1_g, ln1_b, x1, h1,
      w_qkv, wqkv_b, w_proj, wproj_b, w_fc1, wfc1_b, w_fc2, wfc2_b);

  // qkv = h1 @ w_qkv^T, scatter to q/k/vT (coalesced via LDS transpose)
  gemm_bt<0, false><<<dim3((3 * CD) / 64, M / 64), 256, 0, stream>>>(
      h1, wqkv_b, CD, nullptr, nullptr, nullptr, nullptr, q_bf, k_bf, vt_bf);

  // attention (column-chunked two-pass, LDS-staged K/V tiles, prefetch pipelined)
  attn_pass1<<<dim3(NT / 64, BB * NH, CS), 256, 0, stream>>>(q_bf, k_bf, ml);
  attn_pass2<<<dim3(NT / 64, BB * NH, CS), 256, 0, stream>>>(q_bf, k_bf, vt_bf, ml, attn_out, o_part);

  // x2 = x1 + b_proj + (sum o_part) @ w_proj^T   (osum fused into A-staging)
  gemm_bt<3, true><<<dim3(CD / 64, M / 64), 256, 0, stream>>>(
      o_part, wproj_b, CD, b_proj, x1, x2, nullptr, nullptr, nullptr, nullptr);
  ln_kernel<<<M, 128, 0, stream>>>(x2, ln2_g, ln2_b, h2);

  // g = gelu(h2 @ w_fc1^T + b_fc1)   (2-deep prefetch)
  gemm_bt<2, false><<<dim3(HID / 64, M / 64), 256, 0, stream>>>(
      h2, wfc1_b, CD, b_fc1, nullptr, nullptr, g_bf, nullptr, nullptr, nullptr);

  // out = x2 + b_fc2 + g @ w_fc2^T (K=1536, fused residual, 2-deep prefetch)
  gemm_bt<3, false><<<dim3(CD / 64, M / 64), 256, 0, stream>>>(
      g_bf, wfc2_b, HID, b_fc2, x2, out, nullptr, nullptr, nullptr, nullptr);
}